// Round 4
// baseline (37115.494 us; speedup 1.0000x reference)
//
#include <hip/hip_runtime.h>
#include <math.h>

#define FEAT 512
#define NS   4096
#define NQ   8192
#define NC   64
#define G4   2048   // 4*FEAT
#define SLAB 512    // support-slab width for column softmax

__device__ __forceinline__ float sigf(float x) { return 1.0f / (1.0f + expf(-x)); }

// ---------------- small utility kernels ----------------
__global__ void kcopy(float* __restrict__ dst, const float* __restrict__ src, int n) {
    int i = blockIdx.x * blockDim.x + threadIdx.x;
    int st = gridDim.x * blockDim.x;
    for (; i < n; i += st) dst[i] = src[i];
}

__global__ void kzero(float* __restrict__ dst, int n) {
    int i = blockIdx.x * blockDim.x + threadIdx.x;
    int st = gridDim.x * blockDim.x;
    for (; i < n; i += st) dst[i] = 0.0f;
}

__global__ void klog(float* __restrict__ o, int n) {
    int i = blockIdx.x * blockDim.x + threadIdx.x;
    int st = gridDim.x * blockDim.x;
    for (; i < n; i += st) o[i] = logf(o[i]);
}

// pack Wpack[k*4+g][0:1536] = [Wc_ih[g*512+k][0:1024] | Wc_hh[g*512+k][0:512]]
// bpack[k*4+g] = bc[g*512+k]
__global__ void pack_w(float* __restrict__ Wpack, float* __restrict__ bpack,
                       const float* __restrict__ Wc_ih, const float* __restrict__ Wc_hh,
                       const float* __restrict__ bc) {
    int i = blockIdx.x * blockDim.x + threadIdx.x;
    int st = gridDim.x * blockDim.x;
    const int n = G4 * 1536;
    for (; i < n; i += st) {
        int R = i / 1536, j = i - R * 1536;
        int k = R >> 2, g = R & 3;
        int row2 = g * FEAT + k;
        Wpack[i] = (j < 1024) ? Wc_ih[(size_t)row2 * 1024 + j]
                              : Wc_hh[(size_t)row2 * FEAT + (j - 1024)];
        if (j == 0) bpack[R] = bc[row2];
    }
}

// ---------------- GEMM: C = A @ B^T (+bias) ----------------
__global__ __launch_bounds__(256)
void gemm_abt(const float* __restrict__ A, int lda,
              const float* __restrict__ B, int ldb,
              float* __restrict__ C, int ldc,
              const float* __restrict__ bias, int K)
{
    __shared__ float As[8][128];
    __shared__ float Bs[8][128];
    const int row0 = blockIdx.y * 128;
    const int col0 = blockIdx.x * 128;
    const int tid = threadIdx.x;
    const int tr = tid >> 4, tc = tid & 15;
    float acc[8][8];
#pragma unroll
    for (int i = 0; i < 8; ++i)
#pragma unroll
        for (int j = 0; j < 8; ++j) acc[i][j] = 0.0f;

    const int lr = tid >> 1;
    const int lk = (tid & 1) * 4;
    for (int k0 = 0; k0 < K; k0 += 8) {
        float4 av = *(const float4*)(A + (size_t)(row0 + lr) * lda + k0 + lk);
        float4 bv = *(const float4*)(B + (size_t)(col0 + lr) * ldb + k0 + lk);
        As[lk + 0][lr] = av.x; As[lk + 1][lr] = av.y; As[lk + 2][lr] = av.z; As[lk + 3][lr] = av.w;
        Bs[lk + 0][lr] = bv.x; Bs[lk + 1][lr] = bv.y; Bs[lk + 2][lr] = bv.z; Bs[lk + 3][lr] = bv.w;
        __syncthreads();
#pragma unroll
        for (int kk = 0; kk < 8; ++kk) {
            float4 a0 = *(const float4*)&As[kk][tr * 8];
            float4 a1 = *(const float4*)&As[kk][tr * 8 + 4];
            float4 b0 = *(const float4*)&Bs[kk][tc * 8];
            float4 b1 = *(const float4*)&Bs[kk][tc * 8 + 4];
            float a[8] = {a0.x, a0.y, a0.z, a0.w, a1.x, a1.y, a1.z, a1.w};
            float b[8] = {b0.x, b0.y, b0.z, b0.w, b1.x, b1.y, b1.z, b1.w};
#pragma unroll
            for (int i = 0; i < 8; ++i)
#pragma unroll
                for (int j = 0; j < 8; ++j) acc[i][j] += a[i] * b[j];
        }
        __syncthreads();
    }
#pragma unroll
    for (int i = 0; i < 8; ++i) {
        int row = row0 + tr * 8 + i;
#pragma unroll
        for (int j = 0; j < 8; ++j) {
            int col = col0 + tc * 8 + j;
            float v = acc[i][j];
            if (bias) v += bias[col];
            C[(size_t)row * ldc + col] = v;
        }
    }
}

// ---------------- gate GEMM: C = [f|r|h] @ Wslice^T + bias, K = 1536 ----------------
__global__ __launch_bounds__(256)
void gemm_gates(const float* __restrict__ f, const float* __restrict__ r,
                const float* __restrict__ h,
                const float* __restrict__ B,   // slice base, ldb = 1536
                float* __restrict__ C,         // ldc = 512
                const float* __restrict__ bias) // slice base
{
    __shared__ float As[8][128];
    __shared__ float Bs[8][128];
    const int row0 = blockIdx.y * 128;
    const int col0 = blockIdx.x * 128;
    const int tid = threadIdx.x;
    const int tr = tid >> 4, tc = tid & 15;
    float acc[8][8];
#pragma unroll
    for (int i = 0; i < 8; ++i)
#pragma unroll
        for (int j = 0; j < 8; ++j) acc[i][j] = 0.0f;

    const int lr = tid >> 1;
    const int lk = (tid & 1) * 4;
    for (int k0 = 0; k0 < 1536; k0 += 8) {
        const int kg = k0 + lk;
        const float* src = (kg < 512) ? (f + (size_t)(row0 + lr) * FEAT + kg)
                         : (kg < 1024) ? (r + (size_t)(row0 + lr) * FEAT + (kg - 512))
                                       : (h + (size_t)(row0 + lr) * FEAT + (kg - 1024));
        float4 av = *(const float4*)src;
        float4 bv = *(const float4*)(B + (size_t)(col0 + lr) * 1536 + kg);
        As[lk + 0][lr] = av.x; As[lk + 1][lr] = av.y; As[lk + 2][lr] = av.z; As[lk + 3][lr] = av.w;
        Bs[lk + 0][lr] = bv.x; Bs[lk + 1][lr] = bv.y; Bs[lk + 2][lr] = bv.z; Bs[lk + 3][lr] = bv.w;
        __syncthreads();
#pragma unroll
        for (int kk = 0; kk < 8; ++kk) {
            float4 a0 = *(const float4*)&As[kk][tr * 8];
            float4 a1 = *(const float4*)&As[kk][tr * 8 + 4];
            float4 b0 = *(const float4*)&Bs[kk][tc * 8];
            float4 b1 = *(const float4*)&Bs[kk][tc * 8 + 4];
            float a[8] = {a0.x, a0.y, a0.z, a0.w, a1.x, a1.y, a1.z, a1.w};
            float b[8] = {b0.x, b0.y, b0.z, b0.w, b1.x, b1.y, b1.z, b1.w};
#pragma unroll
            for (int i = 0; i < 8; ++i)
#pragma unroll
                for (int j = 0; j < 8; ++j) acc[i][j] += a[i] * b[j];
        }
        __syncthreads();
    }
#pragma unroll
    for (int i = 0; i < 8; ++i) {
        int row = row0 + tr * 8 + i;
#pragma unroll
        for (int j = 0; j < 8; ++j) {
            int col = col0 + tc * 8 + j;
            C[(size_t)row * 512 + col] = acc[i][j] + bias[col];
        }
    }
}

// ---------------- GEMM: C (+)= A @ B ----------------
template<int ACC>
__global__ __launch_bounds__(256)
void gemm_ab(const float* __restrict__ A, int lda,
             const float* __restrict__ B, int ldb,
             float* __restrict__ C, int ldc, int K)
{
    __shared__ float As[16][128];
    __shared__ float Bs[16][64];
    const int row0 = blockIdx.y * 128;
    const int col0 = blockIdx.x * 64;
    const int tid = threadIdx.x;
    const int tr = tid >> 4, tc = tid & 15;
    float acc[8][4];
#pragma unroll
    for (int i = 0; i < 8; ++i)
#pragma unroll
        for (int j = 0; j < 4; ++j) acc[i][j] = 0.0f;

    for (int k0 = 0; k0 < K; k0 += 16) {
#pragma unroll
        for (int p = tid; p < 512; p += 256) {
            int r = p >> 2, kq = (p & 3) * 4;
            float4 av = *(const float4*)(A + (size_t)(row0 + r) * lda + k0 + kq);
            As[kq + 0][r] = av.x; As[kq + 1][r] = av.y; As[kq + 2][r] = av.z; As[kq + 3][r] = av.w;
        }
        {
            int kr = tid >> 4, cq = (tid & 15) * 4;
            float4 bv = *(const float4*)(B + (size_t)(k0 + kr) * ldb + col0 + cq);
            *(float4*)&Bs[kr][cq] = bv;
        }
        __syncthreads();
#pragma unroll
        for (int kk = 0; kk < 16; ++kk) {
            float4 a0 = *(const float4*)&As[kk][tr * 8];
            float4 a1 = *(const float4*)&As[kk][tr * 8 + 4];
            float4 b0 = *(const float4*)&Bs[kk][tc * 4];
            float a[8] = {a0.x, a0.y, a0.z, a0.w, a1.x, a1.y, a1.z, a1.w};
            float b[4] = {b0.x, b0.y, b0.z, b0.w};
#pragma unroll
            for (int i = 0; i < 8; ++i)
#pragma unroll
                for (int j = 0; j < 4; ++j) acc[i][j] += a[i] * b[j];
        }
        __syncthreads();
    }
#pragma unroll
    for (int i = 0; i < 8; ++i) {
        size_t idx = (size_t)(row0 + tr * 8 + i) * ldc + col0 + tc * 4;
#pragma unroll
        for (int j = 0; j < 4; ++j) {
            if (ACC) C[idx + j] += acc[i][j];
            else     C[idx + j]  = acc[i][j];
        }
    }
}

// ---------------- persistent bidirectional LSTM ----------------
// grid: 64 blocks (dir = bid>>5, blk = bid&31), 256 threads, 1 block/CU.
// Sync: per-block flag slots (128B-strided), release-store of step count;
// waiters poll all 32 flags with 32 lanes + ballot (no RMW serialization).
// h output goes to Hout AFTER the flag store (off the critical path).
__global__ __launch_bounds__(256, 1)
void lstm_persist(const float* __restrict__ Xf, const float* __restrict__ Xb,
                  const float* __restrict__ Wf, const float* __restrict__ Wb,
                  float* __restrict__ hbuf, unsigned int* __restrict__ flags,
                  float* __restrict__ Hf, float* __restrict__ Hb)
{
    __shared__ float w_lds[64 * FEAT];   // 128 KB: row (e*4+g), col k
    __shared__ float hs[FEAT];

    const int bid = blockIdx.x;
    const int dir = bid >> 5;
    const int blk = bid & 31;
    const int tid = threadIdx.x;
    const float* W = dir ? Wb : Wf;
    const float* X = dir ? Xb : Xf;
    float* hb = hbuf + dir * 2 * FEAT;                 // [parity][512]
    unsigned int* fl = flags + dir * 32 * 32;          // 32 flags, stride 32 dwords
    float* Hout = dir ? Hb : Hf;

    // stage W rows: global row (g*512 + blk*16 + e) -> lds row (e*4+g)
    for (int idx = tid * 4; idx < 64 * FEAT; idx += 1024) {
        int row_ld = idx >> 9, col = idx & 511;
        int grow = (row_ld & 3) * FEAT + blk * 16 + (row_ld >> 2);
        float4 wv = *(const float4*)(W + (size_t)grow * FEAT + col);
        *(float4*)&w_lds[row_ld * FEAT + col] = wv;
    }
    __syncthreads();

    const int e = tid >> 4, l = tid & 15;
    const int hidx = blk * 16 + e;
    const int lane = tid & 63;
    float c_reg = 0.0f;

    for (int t = 0; t < NS; ++t) {
        const int trow = dir ? (NS - 1 - t) : t;
        const float* Xrow = X + (size_t)trow * G4;
        // prefetch gate-bias terms (independent of h) — hides under the wait
        float x0 = 0.f, x1 = 0.f, x2 = 0.f, x3 = 0.f;
        if (l == 0) {
            x0 = Xrow[hidx];            x1 = Xrow[FEAT + hidx];
            x2 = Xrow[2 * FEAT + hidx]; x3 = Xrow[3 * FEAT + hidx];
        }
        // wait for h_{t-1}: every wave polls all 32 flags (lanes 0..31)
        if (t > 0) {
            for (;;) {
                unsigned v = (lane < 32)
                    ? __hip_atomic_load(&fl[lane * 32], __ATOMIC_ACQUIRE,
                                        __HIP_MEMORY_SCOPE_AGENT)
                    : 0xffffffffu;
                if (__all(v >= (unsigned)t)) break;
            }
        }
        // gather h_{t-1} (agent-scope loads: bypass stale caches)
        const float* hp = hb + (t & 1) * FEAT;
        hs[tid]       = __hip_atomic_load(hp + tid,       __ATOMIC_RELAXED, __HIP_MEMORY_SCOPE_AGENT);
        hs[tid + 256] = __hip_atomic_load(hp + tid + 256, __ATOMIC_RELAXED, __HIP_MEMORY_SCOPE_AGENT);
        __syncthreads();

        float dots[4];
#pragma unroll
        for (int g = 0; g < 4; ++g) {
            const float* w = &w_lds[(e * 4 + g) * FEAT];
            float s = 0.0f;
#pragma unroll
            for (int j = 0; j < 8; ++j) {
                int col = l * 4 + j * 64;
                float4 wv = *(const float4*)&w[col];
                float4 hv = *(const float4*)&hs[col];
                s += wv.x * hv.x + wv.y * hv.y + wv.z * hv.z + wv.w * hv.w;
            }
#pragma unroll
            for (int off = 8; off >= 1; off >>= 1) s += __shfl_xor(s, off, 64);
            dots[g] = s;
        }
        float hv = 0.0f;
        if (l == 0) {
            float gi = dots[0] + x0, gf = dots[1] + x1;
            float gg = dots[2] + x2, go = dots[3] + x3;
            float cn = sigf(gf) * c_reg + sigf(gi) * tanhf(gg);
            hv = sigf(go) * tanhf(cn);
            c_reg = cn;
            __hip_atomic_store(hb + (1 - (t & 1)) * FEAT + hidx, hv,
                               __ATOMIC_RELAXED, __HIP_MEMORY_SCOPE_AGENT);
        }
        __syncthreads();   // drains vmcnt: h stores visible before the release flag
        if (tid == 0)
            __hip_atomic_store(&fl[blk * 32], (unsigned)(t + 1),
                               __ATOMIC_RELEASE, __HIP_MEMORY_SCOPE_AGENT);
        // Hout store AFTER the flag — off the critical path, drains during next wait
        if (l == 0) Hout[(size_t)trow * FEAT + hidx] = hv;
    }
}

// ---------------- fused G assembly + row-normalize ----------------
// G = S + Hf + Hb ; Gn = G / (||G|| + 1e-5)
__global__ __launch_bounds__(256)
void gnorm_fuse(const float* __restrict__ S, const float* __restrict__ Hf,
                const float* __restrict__ Hb, float* __restrict__ G,
                float* __restrict__ Gn)
{
    const int row = blockIdx.x;
    const size_t base = (size_t)row * FEAT;
    const int tid = threadIdx.x;
    float v0 = S[base + tid]       + Hf[base + tid]       + Hb[base + tid];
    float v1 = S[base + tid + 256] + Hf[base + tid + 256] + Hb[base + tid + 256];
    G[base + tid] = v0;
    G[base + tid + 256] = v1;
    float s = v0 * v0 + v1 * v1;
#pragma unroll
    for (int off = 32; off >= 1; off >>= 1) s += __shfl_xor(s, off, 64);
    __shared__ float red[4];
    if ((tid & 63) == 0) red[tid >> 6] = s;
    __syncthreads();
    float tot = red[0] + red[1] + red[2] + red[3];
    float inv = 1.0f / (sqrtf(tot) + 1e-5f);
    Gn[base + tid] = v0 * inv;
    Gn[base + tid + 256] = v1 * inv;
}

// ---------------- column softmax stats over a [NQ x SLAB] slab ----------------
__global__ __launch_bounds__(256)
void colstats_partial(const float* __restrict__ A, float* __restrict__ pm,
                      float* __restrict__ pz)
{
    const int col = blockIdx.x * 256 + threadIdx.x;      // 0..511
    const int r0 = blockIdx.y * 256;
    float m = -3.0e38f, z = 0.0f;
    for (int r = 0; r < 256; ++r) {
        float v = A[(size_t)(r0 + r) * SLAB + col];
        if (v > m) { z = z * expf(m - v) + 1.0f; m = v; }
        else       { z += expf(v - m); }
    }
    pm[(size_t)blockIdx.y * SLAB + col] = m;
    pz[(size_t)blockIdx.y * SLAB + col] = z;
}

__global__ __launch_bounds__(256)
void colstats_combine(const float* __restrict__ pm, const float* __restrict__ pz,
                      float* __restrict__ cm, float* __restrict__ ciz)
{
    const int col = blockIdx.x * 256 + threadIdx.x;      // 0..511
    float m = -3.0e38f;
    for (int p = 0; p < 32; ++p) m = fmaxf(m, pm[(size_t)p * SLAB + col]);
    float z = 0.0f;
    for (int p = 0; p < 32; ++p) z += pz[(size_t)p * SLAB + col] * expf(pm[(size_t)p * SLAB + col] - m);
    cm[col] = m;
    ciz[col] = 1.0f / z;
}

__global__ void exp_transform(float* __restrict__ A, const float* __restrict__ cm,
                              const float* __restrict__ ciz)
{
    int i = blockIdx.x * blockDim.x + threadIdx.x;
    const int st = gridDim.x * blockDim.x;
    const int n = NQ * SLAB;
    for (; i < n; i += st) {
        int col = i & (SLAB - 1);
        A[i] = expf(A[i] - cm[col]) * ciz[col];
    }
}

// ---------------- FCE cell on one k-slice of 128 ----------------
__global__ void cell_slice(const float* __restrict__ gslab, float* __restrict__ cst,
                           float* __restrict__ hnext, const float* __restrict__ f,
                           int k0)
{
    int i = blockIdx.x * blockDim.x + threadIdx.x;
    const int st = gridDim.x * blockDim.x;
    const int n = NQ * 128;
    for (; i < n; i += st) {
        int q = i >> 7, kk = i & 127;
        float4 g = *(const float4*)(gslab + (size_t)q * 512 + kk * 4);
        int idx = q * FEAT + k0 + kk;
        float cold = cst[idx];
        float cn = sigf(g.y) * cold + sigf(g.x) * tanhf(g.z);
        float hn = sigf(g.w) * tanhf(cn) + f[idx];
        cst[idx] = cn;
        hnext[idx] = hn;
    }
}

// ---------------- launch ----------------
extern "C" void kernel_launch(void* const* d_in, const int* in_sizes, int n_in,
                              void* d_out, int out_size, void* d_ws, size_t ws_size,
                              hipStream_t stream)
{
    (void)in_sizes; (void)n_in; (void)out_size; (void)ws_size;
    const float* S     = (const float*)d_in[0];
    const float* f     = (const float*)d_in[1];
    const float* Y     = (const float*)d_in[2];
    const float* Wf_ih = (const float*)d_in[3];
    const float* Wf_hh = (const float*)d_in[4];
    const float* bf    = (const float*)d_in[5];
    const float* Wb_ih = (const float*)d_in[6];
    const float* Wb_hh = (const float*)d_in[7];
    const float* bb    = (const float*)d_in[8];
    const float* Wc_ih = (const float*)d_in[9];
    const float* Wc_hh = (const float*)d_in[10];
    const float* bc    = (const float*)d_in[11];
    float* out = (float*)d_out;

    float* ws = (float*)d_ws;
    // region 0: 16M floats, phase A/B = Xf|Xb ; phase C = r|h0|h1|cst
    float* Xf   = ws;                       // 8M
    float* Xb   = ws + (size_t)8 * 1024 * 1024;
    float* r    = ws;                       // 4M each
    float* h0   = ws + (size_t)4 * 1024 * 1024;
    float* h1   = ws + (size_t)8 * 1024 * 1024;
    float* cst  = ws + (size_t)12 * 1024 * 1024;
    size_t off  = (size_t)16 * 1024 * 1024;
    auto alloc = [&](size_t n) { float* p = ws + off; off += n; return p; };
    float* Pslab = alloc((size_t)NQ * SLAB);   // 4M (gslab; also Hf|Hb during LSTM)
    float* G     = alloc((size_t)NS * FEAT);   // 2M
    float* Gn    = alloc((size_t)NS * FEAT);   // 2M
    float* Wpack = alloc((size_t)G4 * 1536);   // 3M
    float* bpack = alloc(G4);
    float* pm    = alloc((size_t)32 * SLAB);
    float* pz    = alloc((size_t)32 * SLAB);
    float* cm    = alloc(SLAB);
    float* ciz   = alloc(SLAB);
    float* hbuf  = alloc(4 * FEAT);            // [dir][parity][512]
    float* flags = alloc(2048);                // 2 dirs x 32 flags x 32-dword stride

    // Hf/Hb alias Pslab (free during the LSTM phase; consumed by gnorm_fuse
    // before Phase C first touches Pslab)
    float* Hf = Pslab;
    float* Hb = Pslab + (size_t)2 * 1024 * 1024;

    const dim3 B256(256);

    // ---- Phase A: Xf = S@Wf_ih^T+bf, Xb = S@Wb_ih^T+bb ----
    gemm_abt<<<dim3(16, 32), B256, 0, stream>>>(S, FEAT, Wf_ih, FEAT, Xf, G4, bf, FEAT);
    gemm_abt<<<dim3(16, 32), B256, 0, stream>>>(S, FEAT, Wb_ih, FEAT, Xb, G4, bb, FEAT);

    // ---- Phase B: persistent bidirectional LSTM ----
    kzero<<<dim3(8), B256, 0, stream>>>(hbuf, 4 * FEAT + 2048);  // hbuf + flags contiguous
    lstm_persist<<<dim3(64), B256, 0, stream>>>(Xf, Xb, Wf_hh, Wb_hh, hbuf,
                                                (unsigned int*)flags, Hf, Hb);
    gnorm_fuse<<<dim3(NS), B256, 0, stream>>>(S, Hf, Hb, G, Gn);

    // ---- Phase C prep ----
    pack_w<<<dim3(2048), B256, 0, stream>>>(Wpack, bpack, Wc_ih, Wc_hh, bc);
    kcopy<<<dim3(1024), B256, 0, stream>>>(h0, f, NQ * FEAT);   // h = f
    kzero<<<dim3(1024), B256, 0, stream>>>(cst, NQ * FEAT);     // c = 0

    // ---- Phase C: K=3 FCE iterations ----
    for (int it = 0; it < 3; ++it) {
        float* hc = (it & 1) ? h1 : h0;
        float* hx = (it & 1) ? h0 : h1;
        // r = softmax_col(hc @ G^T) @ G, slab by slab
        for (int sb = 0; sb < NS / SLAB; ++sb) {
            const float* Gs = G + (size_t)sb * SLAB * FEAT;
            gemm_abt<<<dim3(4, 64), B256, 0, stream>>>(hc, FEAT, Gs, FEAT, Pslab, SLAB, nullptr, FEAT);
            colstats_partial<<<dim3(2, 32), B256, 0, stream>>>(Pslab, pm, pz);
            colstats_combine<<<dim3(2), B256, 0, stream>>>(pm, pz, cm, ciz);
            exp_transform<<<dim3(1024), B256, 0, stream>>>(Pslab, cm, ciz);
            if (sb == 0) gemm_ab<0><<<dim3(8, 64), B256, 0, stream>>>(Pslab, SLAB, Gs, FEAT, r, FEAT, SLAB);
            else         gemm_ab<1><<<dim3(8, 64), B256, 0, stream>>>(Pslab, SLAB, Gs, FEAT, r, FEAT, SLAB);
        }
        // gates + cell, 4 k-slices of 128 (N=512 each), gslab aliases Pslab
        for (int sl = 0; sl < 4; ++sl) {
            gemm_gates<<<dim3(4, 64), B256, 0, stream>>>(f, r, hc,
                Wpack + (size_t)sl * 512 * 1536, Pslab, bpack + sl * 512);
            cell_slice<<<dim3(1024), B256, 0, stream>>>(Pslab, cst, hx, f, sl * 128);
        }
    }

    // ---- Phase D: out = log(softmax_col(h @ Gn^T) @ Y), slab by slab ----
    for (int sb = 0; sb < NS / SLAB; ++sb) {
        const float* Gs = Gn + (size_t)sb * SLAB * FEAT;
        gemm_abt<<<dim3(4, 64), B256, 0, stream>>>(h1, FEAT, Gs, FEAT, Pslab, SLAB, nullptr, FEAT);
        colstats_partial<<<dim3(2, 32), B256, 0, stream>>>(Pslab, pm, pz);
        colstats_combine<<<dim3(2), B256, 0, stream>>>(pm, pz, cm, ciz);
        exp_transform<<<dim3(1024), B256, 0, stream>>>(Pslab, cm, ciz);
        if (sb == 0) gemm_ab<0><<<dim3(1, 64), B256, 0, stream>>>(Pslab, SLAB, Y + (size_t)sb * SLAB * NC, NC, out, NC, SLAB);
        else         gemm_ab<1><<<dim3(1, 64), B256, 0, stream>>>(Pslab, SLAB, Y + (size_t)sb * SLAB * NC, NC, out, NC, SLAB);
    }
    klog<<<dim3(512), B256, 0, stream>>>(out, NQ * NC);
}

// Round 5
// 22610.802 us; speedup vs baseline: 1.6415x; 1.6415x over previous
//
#include <hip/hip_runtime.h>
#include <math.h>

#define FEAT 512
#define NS   4096
#define NQ   8192
#define NC   64
#define G4   2048   // 4*FEAT
#define SLAB 512    // support-slab width for column softmax
#define SENT 1.0e30f

__device__ __forceinline__ float sigf(float x) { return 1.0f / (1.0f + expf(-x)); }

// ---------------- small utility kernels ----------------
__global__ void kcopy(float* __restrict__ dst, const float* __restrict__ src, int n) {
    int i = blockIdx.x * blockDim.x + threadIdx.x;
    int st = gridDim.x * blockDim.x;
    for (; i < n; i += st) dst[i] = src[i];
}

__global__ void kzero(float* __restrict__ dst, int n) {
    int i = blockIdx.x * blockDim.x + threadIdx.x;
    int st = gridDim.x * blockDim.x;
    for (; i < n; i += st) dst[i] = 0.0f;
}

__global__ void kfill(float* __restrict__ dst, float v, int n) {
    int i = blockIdx.x * blockDim.x + threadIdx.x;
    int st = gridDim.x * blockDim.x;
    for (; i < n; i += st) dst[i] = v;
}

__global__ void klog(float* __restrict__ o, int n) {
    int i = blockIdx.x * blockDim.x + threadIdx.x;
    int st = gridDim.x * blockDim.x;
    for (; i < n; i += st) o[i] = logf(o[i]);
}

// pack Wpack[k*4+g][0:1536] = [Wc_ih[g*512+k][0:1024] | Wc_hh[g*512+k][0:512]]
// bpack[k*4+g] = bc[g*512+k]
__global__ void pack_w(float* __restrict__ Wpack, float* __restrict__ bpack,
                       const float* __restrict__ Wc_ih, const float* __restrict__ Wc_hh,
                       const float* __restrict__ bc) {
    int i = blockIdx.x * blockDim.x + threadIdx.x;
    int st = gridDim.x * blockDim.x;
    const int n = G4 * 1536;
    for (; i < n; i += st) {
        int R = i / 1536, j = i - R * 1536;
        int k = R >> 2, g = R & 3;
        int row2 = g * FEAT + k;
        Wpack[i] = (j < 1024) ? Wc_ih[(size_t)row2 * 1024 + j]
                              : Wc_hh[(size_t)row2 * FEAT + (j - 1024)];
        if (j == 0) bpack[R] = bc[row2];
    }
}

// ---------------- GEMM: C = A @ B^T (+bias) ----------------
__global__ __launch_bounds__(256)
void gemm_abt(const float* __restrict__ A, int lda,
              const float* __restrict__ B, int ldb,
              float* __restrict__ C, int ldc,
              const float* __restrict__ bias, int K)
{
    __shared__ float As[8][128];
    __shared__ float Bs[8][128];
    const int row0 = blockIdx.y * 128;
    const int col0 = blockIdx.x * 128;
    const int tid = threadIdx.x;
    const int tr = tid >> 4, tc = tid & 15;
    float acc[8][8];
#pragma unroll
    for (int i = 0; i < 8; ++i)
#pragma unroll
        for (int j = 0; j < 8; ++j) acc[i][j] = 0.0f;

    const int lr = tid >> 1;
    const int lk = (tid & 1) * 4;
    for (int k0 = 0; k0 < K; k0 += 8) {
        float4 av = *(const float4*)(A + (size_t)(row0 + lr) * lda + k0 + lk);
        float4 bv = *(const float4*)(B + (size_t)(col0 + lr) * ldb + k0 + lk);
        As[lk + 0][lr] = av.x; As[lk + 1][lr] = av.y; As[lk + 2][lr] = av.z; As[lk + 3][lr] = av.w;
        Bs[lk + 0][lr] = bv.x; Bs[lk + 1][lr] = bv.y; Bs[lk + 2][lr] = bv.z; Bs[lk + 3][lr] = bv.w;
        __syncthreads();
#pragma unroll
        for (int kk = 0; kk < 8; ++kk) {
            float4 a0 = *(const float4*)&As[kk][tr * 8];
            float4 a1 = *(const float4*)&As[kk][tr * 8 + 4];
            float4 b0 = *(const float4*)&Bs[kk][tc * 8];
            float4 b1 = *(const float4*)&Bs[kk][tc * 8 + 4];
            float a[8] = {a0.x, a0.y, a0.z, a0.w, a1.x, a1.y, a1.z, a1.w};
            float b[8] = {b0.x, b0.y, b0.z, b0.w, b1.x, b1.y, b1.z, b1.w};
#pragma unroll
            for (int i = 0; i < 8; ++i)
#pragma unroll
                for (int j = 0; j < 8; ++j) acc[i][j] += a[i] * b[j];
        }
        __syncthreads();
    }
#pragma unroll
    for (int i = 0; i < 8; ++i) {
        int row = row0 + tr * 8 + i;
#pragma unroll
        for (int j = 0; j < 8; ++j) {
            int col = col0 + tc * 8 + j;
            float v = acc[i][j];
            if (bias) v += bias[col];
            C[(size_t)row * ldc + col] = v;
        }
    }
}

// ---------------- gate GEMM: C = [f|r|h] @ Wslice^T + bias, K = 1536 ----------------
__global__ __launch_bounds__(256)
void gemm_gates(const float* __restrict__ f, const float* __restrict__ r,
                const float* __restrict__ h,
                const float* __restrict__ B,   // slice base, ldb = 1536
                float* __restrict__ C,         // ldc = 512
                const float* __restrict__ bias) // slice base
{
    __shared__ float As[8][128];
    __shared__ float Bs[8][128];
    const int row0 = blockIdx.y * 128;
    const int col0 = blockIdx.x * 128;
    const int tid = threadIdx.x;
    const int tr = tid >> 4, tc = tid & 15;
    float acc[8][8];
#pragma unroll
    for (int i = 0; i < 8; ++i)
#pragma unroll
        for (int j = 0; j < 8; ++j) acc[i][j] = 0.0f;

    const int lr = tid >> 1;
    const int lk = (tid & 1) * 4;
    for (int k0 = 0; k0 < 1536; k0 += 8) {
        const int kg = k0 + lk;
        const float* src = (kg < 512) ? (f + (size_t)(row0 + lr) * FEAT + kg)
                         : (kg < 1024) ? (r + (size_t)(row0 + lr) * FEAT + (kg - 512))
                                       : (h + (size_t)(row0 + lr) * FEAT + (kg - 1024));
        float4 av = *(const float4*)src;
        float4 bv = *(const float4*)(B + (size_t)(col0 + lr) * 1536 + kg);
        As[lk + 0][lr] = av.x; As[lk + 1][lr] = av.y; As[lk + 2][lr] = av.z; As[lk + 3][lr] = av.w;
        Bs[lk + 0][lr] = bv.x; Bs[lk + 1][lr] = bv.y; Bs[lk + 2][lr] = bv.z; Bs[lk + 3][lr] = bv.w;
        __syncthreads();
#pragma unroll
        for (int kk = 0; kk < 8; ++kk) {
            float4 a0 = *(const float4*)&As[kk][tr * 8];
            float4 a1 = *(const float4*)&As[kk][tr * 8 + 4];
            float4 b0 = *(const float4*)&Bs[kk][tc * 8];
            float4 b1 = *(const float4*)&Bs[kk][tc * 8 + 4];
            float a[8] = {a0.x, a0.y, a0.z, a0.w, a1.x, a1.y, a1.z, a1.w};
            float b[8] = {b0.x, b0.y, b0.z, b0.w, b1.x, b1.y, b1.z, b1.w};
#pragma unroll
            for (int i = 0; i < 8; ++i)
#pragma unroll
                for (int j = 0; j < 8; ++j) acc[i][j] += a[i] * b[j];
        }
        __syncthreads();
    }
#pragma unroll
    for (int i = 0; i < 8; ++i) {
        int row = row0 + tr * 8 + i;
#pragma unroll
        for (int j = 0; j < 8; ++j) {
            int col = col0 + tc * 8 + j;
            C[(size_t)row * 512 + col] = acc[i][j] + bias[col];
        }
    }
}

// ---------------- GEMM: C (+)= A @ B ----------------
template<int ACC>
__global__ __launch_bounds__(256)
void gemm_ab(const float* __restrict__ A, int lda,
             const float* __restrict__ B, int ldb,
             float* __restrict__ C, int ldc, int K)
{
    __shared__ float As[16][128];
    __shared__ float Bs[16][64];
    const int row0 = blockIdx.y * 128;
    const int col0 = blockIdx.x * 64;
    const int tid = threadIdx.x;
    const int tr = tid >> 4, tc = tid & 15;
    float acc[8][4];
#pragma unroll
    for (int i = 0; i < 8; ++i)
#pragma unroll
        for (int j = 0; j < 4; ++j) acc[i][j] = 0.0f;

    for (int k0 = 0; k0 < K; k0 += 16) {
#pragma unroll
        for (int p = tid; p < 512; p += 256) {
            int r = p >> 2, kq = (p & 3) * 4;
            float4 av = *(const float4*)(A + (size_t)(row0 + r) * lda + k0 + kq);
            As[kq + 0][r] = av.x; As[kq + 1][r] = av.y; As[kq + 2][r] = av.z; As[kq + 3][r] = av.w;
        }
        {
            int kr = tid >> 4, cq = (tid & 15) * 4;
            float4 bv = *(const float4*)(B + (size_t)(k0 + kr) * ldb + col0 + cq);
            *(float4*)&Bs[kr][cq] = bv;
        }
        __syncthreads();
#pragma unroll
        for (int kk = 0; kk < 16; ++kk) {
            float4 a0 = *(const float4*)&As[kk][tr * 8];
            float4 a1 = *(const float4*)&As[kk][tr * 8 + 4];
            float4 b0 = *(const float4*)&Bs[kk][tc * 4];
            float a[8] = {a0.x, a0.y, a0.z, a0.w, a1.x, a1.y, a1.z, a1.w};
            float b[4] = {b0.x, b0.y, b0.z, b0.w};
#pragma unroll
            for (int i = 0; i < 8; ++i)
#pragma unroll
                for (int j = 0; j < 4; ++j) acc[i][j] += a[i] * b[j];
        }
        __syncthreads();
    }
#pragma unroll
    for (int i = 0; i < 8; ++i) {
        size_t idx = (size_t)(row0 + tr * 8 + i) * ldc + col0 + tc * 4;
#pragma unroll
        for (int j = 0; j < 4; ++j) {
            if (ACC) C[idx + j] += acc[i][j];
            else     C[idx + j]  = acc[i][j];
        }
    }
}

// ---------------- persistent bidirectional LSTM (sentinel data-polling) ----------------
// grid: 64 blocks (dir = bid>>5, blk = bid&31), 256 threads, 1 block/CU.
// Step t's h vector lives in its own row H[trow]; rows are pre-filled with
// SENT. Producers store h via relaxed agent atomics; consumers poll the data
// itself (each thread its own 2 floats). One LLC round trip per step, no
// flags, no RMW, no fences. W_hh slice lives in registers (32 float4/thread).
__global__ __launch_bounds__(256, 1)
void lstm_persist(const float* __restrict__ Xf, const float* __restrict__ Xb,
                  const float* __restrict__ Wf, const float* __restrict__ Wb,
                  float* __restrict__ Hf, float* __restrict__ Hb)
{
    __shared__ float hs[FEAT];

    const int bid = blockIdx.x;
    const int dir = bid >> 5;
    const int blk = bid & 31;
    const int tid = threadIdx.x;
    const float* W = dir ? Wb : Wf;
    const float* X = dir ? Xb : Xf;
    float* H = dir ? Hb : Hf;

    const int e = tid >> 4, l = tid & 15;
    const int hidx = blk * 16 + e;

    // this thread's 128 W_hh coefficients -> registers (static indexing only)
    float4 wr[32];
#pragma unroll
    for (int g = 0; g < 4; ++g)
#pragma unroll
        for (int j = 0; j < 8; ++j)
            wr[g * 8 + j] = *(const float4*)(W + (size_t)(g * FEAT + hidx) * FEAT + l * 4 + j * 64);

    float c_reg = 0.0f;

    for (int t = 0; t < NS; ++t) {
        const int trow = dir ? (NS - 1 - t) : t;
        const float* Xrow = X + (size_t)trow * G4;
        // prefetch gate-bias terms (independent of h) — hides under the poll
        float x0 = 0.f, x1 = 0.f, x2 = 0.f, x3 = 0.f;
        if (l == 0) {
            x0 = Xrow[hidx];            x1 = Xrow[FEAT + hidx];
            x2 = Xrow[2 * FEAT + hidx]; x3 = Xrow[3 * FEAT + hidx];
        }
        if (t > 0) {
            const int prow = dir ? (trow + 1) : (trow - 1);
            const float* Hp = H + (size_t)prow * FEAT;
            float v0, v1;
            do { v0 = __hip_atomic_load(Hp + tid, __ATOMIC_RELAXED,
                                        __HIP_MEMORY_SCOPE_AGENT); } while (v0 == SENT);
            do { v1 = __hip_atomic_load(Hp + tid + 256, __ATOMIC_RELAXED,
                                        __HIP_MEMORY_SCOPE_AGENT); } while (v1 == SENT);
            hs[tid] = v0; hs[tid + 256] = v1;
        } else {
            hs[tid] = 0.0f; hs[tid + 256] = 0.0f;
        }
        __syncthreads();

        float4 hv4[8];
#pragma unroll
        for (int j = 0; j < 8; ++j) hv4[j] = *(const float4*)&hs[l * 4 + j * 64];

        float dots[4];
#pragma unroll
        for (int g = 0; g < 4; ++g) {
            float s = 0.0f;
#pragma unroll
            for (int j = 0; j < 8; ++j) {
                float4 w4 = wr[g * 8 + j];
                float4 h4 = hv4[j];
                s += w4.x * h4.x + w4.y * h4.y + w4.z * h4.z + w4.w * h4.w;
            }
#pragma unroll
            for (int off = 8; off >= 1; off >>= 1) s += __shfl_xor(s, off, 64);
            dots[g] = s;
        }
        if (l == 0) {
            float gi = dots[0] + x0, gf = dots[1] + x1;
            float gg = dots[2] + x2, go = dots[3] + x3;
            float cn = sigf(gf) * c_reg + sigf(gi) * tanhf(gg);
            float hv = sigf(go) * tanhf(cn);
            c_reg = cn;
            __hip_atomic_store(H + (size_t)trow * FEAT + hidx, hv,
                               __ATOMIC_RELAXED, __HIP_MEMORY_SCOPE_AGENT);
        }
        __syncthreads();   // hs reuse guard for next iteration
    }
}

// ---------------- fused G assembly + row-normalize ----------------
// G = S + Hf + Hb ; Gn = G / (||G|| + 1e-5)
__global__ __launch_bounds__(256)
void gnorm_fuse(const float* __restrict__ S, const float* __restrict__ Hf,
                const float* __restrict__ Hb, float* __restrict__ G,
                float* __restrict__ Gn)
{
    const int row = blockIdx.x;
    const size_t base = (size_t)row * FEAT;
    const int tid = threadIdx.x;
    float v0 = S[base + tid]       + Hf[base + tid]       + Hb[base + tid];
    float v1 = S[base + tid + 256] + Hf[base + tid + 256] + Hb[base + tid + 256];
    G[base + tid] = v0;
    G[base + tid + 256] = v1;
    float s = v0 * v0 + v1 * v1;
#pragma unroll
    for (int off = 32; off >= 1; off >>= 1) s += __shfl_xor(s, off, 64);
    __shared__ float red[4];
    if ((tid & 63) == 0) red[tid >> 6] = s;
    __syncthreads();
    float tot = red[0] + red[1] + red[2] + red[3];
    float inv = 1.0f / (sqrtf(tot) + 1e-5f);
    Gn[base + tid] = v0 * inv;
    Gn[base + tid + 256] = v1 * inv;
}

// ---------------- column softmax stats over a [NQ x SLAB] slab ----------------
__global__ __launch_bounds__(256)
void colstats_partial(const float* __restrict__ A, float* __restrict__ pm,
                      float* __restrict__ pz)
{
    const int col = blockIdx.x * 256 + threadIdx.x;      // 0..511
    const int r0 = blockIdx.y * 256;
    float m = -3.0e38f, z = 0.0f;
    for (int r = 0; r < 256; ++r) {
        float v = A[(size_t)(r0 + r) * SLAB + col];
        if (v > m) { z = z * expf(m - v) + 1.0f; m = v; }
        else       { z += expf(v - m); }
    }
    pm[(size_t)blockIdx.y * SLAB + col] = m;
    pz[(size_t)blockIdx.y * SLAB + col] = z;
}

__global__ __launch_bounds__(256)
void colstats_combine(const float* __restrict__ pm, const float* __restrict__ pz,
                      float* __restrict__ cm, float* __restrict__ ciz)
{
    const int col = blockIdx.x * 256 + threadIdx.x;      // 0..511
    float m = -3.0e38f;
    for (int p = 0; p < 32; ++p) m = fmaxf(m, pm[(size_t)p * SLAB + col]);
    float z = 0.0f;
    for (int p = 0; p < 32; ++p) z += pz[(size_t)p * SLAB + col] * expf(pm[(size_t)p * SLAB + col] - m);
    cm[col] = m;
    ciz[col] = 1.0f / z;
}

__global__ void exp_transform(float* __restrict__ A, const float* __restrict__ cm,
                              const float* __restrict__ ciz)
{
    int i = blockIdx.x * blockDim.x + threadIdx.x;
    const int st = gridDim.x * blockDim.x;
    const int n = NQ * SLAB;
    for (; i < n; i += st) {
        int col = i & (SLAB - 1);
        A[i] = expf(A[i] - cm[col]) * ciz[col];
    }
}

// ---------------- FCE cell on one k-slice of 128 ----------------
__global__ void cell_slice(const float* __restrict__ gslab, float* __restrict__ cst,
                           float* __restrict__ hnext, const float* __restrict__ f,
                           int k0)
{
    int i = blockIdx.x * blockDim.x + threadIdx.x;
    const int st = gridDim.x * blockDim.x;
    const int n = NQ * 128;
    for (; i < n; i += st) {
        int q = i >> 7, kk = i & 127;
        float4 g = *(const float4*)(gslab + (size_t)q * 512 + kk * 4);
        int idx = q * FEAT + k0 + kk;
        float cold = cst[idx];
        float cn = sigf(g.y) * cold + sigf(g.x) * tanhf(g.z);
        float hn = sigf(g.w) * tanhf(cn) + f[idx];
        cst[idx] = cn;
        hnext[idx] = hn;
    }
}

// ---------------- launch ----------------
extern "C" void kernel_launch(void* const* d_in, const int* in_sizes, int n_in,
                              void* d_out, int out_size, void* d_ws, size_t ws_size,
                              hipStream_t stream)
{
    (void)in_sizes; (void)n_in; (void)out_size; (void)ws_size;
    const float* S     = (const float*)d_in[0];
    const float* f     = (const float*)d_in[1];
    const float* Y     = (const float*)d_in[2];
    const float* Wf_ih = (const float*)d_in[3];
    const float* Wf_hh = (const float*)d_in[4];
    const float* bf    = (const float*)d_in[5];
    const float* Wb_ih = (const float*)d_in[6];
    const float* Wb_hh = (const float*)d_in[7];
    const float* bb    = (const float*)d_in[8];
    const float* Wc_ih = (const float*)d_in[9];
    const float* Wc_hh = (const float*)d_in[10];
    const float* bc    = (const float*)d_in[11];
    float* out = (float*)d_out;

    float* ws = (float*)d_ws;
    // region 0: 16M floats, phase A/B = Xf|Xb ; phase C = r|h0|h1|cst
    float* Xf   = ws;                       // 8M
    float* Xb   = ws + (size_t)8 * 1024 * 1024;
    float* r    = ws;                       // 4M each
    float* h0   = ws + (size_t)4 * 1024 * 1024;
    float* h1   = ws + (size_t)8 * 1024 * 1024;
    float* cst  = ws + (size_t)12 * 1024 * 1024;
    size_t off  = (size_t)16 * 1024 * 1024;
    auto alloc = [&](size_t n) { float* p = ws + off; off += n; return p; };
    float* Pslab = alloc((size_t)NQ * SLAB);   // 4M (gslab; also Hf|Hb during LSTM)
    float* G     = alloc((size_t)NS * FEAT);   // 2M
    float* Gn    = alloc((size_t)NS * FEAT);   // 2M
    float* Wpack = alloc((size_t)G4 * 1536);   // 3M
    float* bpack = alloc(G4);
    float* pm    = alloc((size_t)32 * SLAB);
    float* pz    = alloc((size_t)32 * SLAB);
    float* cm    = alloc(SLAB);
    float* ciz   = alloc(SLAB);

    // Hf/Hb alias Pslab (free during the LSTM phase; consumed by gnorm_fuse
    // before Phase C first touches Pslab). 2M floats each.
    float* Hf = Pslab;
    float* Hb = Pslab + (size_t)2 * 1024 * 1024;

    const dim3 B256(256);

    // ---- Phase A: Xf = S@Wf_ih^T+bf, Xb = S@Wb_ih^T+bb ----
    gemm_abt<<<dim3(16, 32), B256, 0, stream>>>(S, FEAT, Wf_ih, FEAT, Xf, G4, bf, FEAT);
    gemm_abt<<<dim3(16, 32), B256, 0, stream>>>(S, FEAT, Wb_ih, FEAT, Xb, G4, bb, FEAT);

    // ---- Phase B: persistent bidirectional LSTM ----
    kfill<<<dim3(2048), B256, 0, stream>>>(Pslab, SENT, 4 * 1024 * 1024);  // Hf+Hb sentinel
    lstm_persist<<<dim3(64), B256, 0, stream>>>(Xf, Xb, Wf_hh, Wb_hh, Hf, Hb);
    gnorm_fuse<<<dim3(NS), B256, 0, stream>>>(S, Hf, Hb, G, Gn);

    // ---- Phase C prep ----
    pack_w<<<dim3(2048), B256, 0, stream>>>(Wpack, bpack, Wc_ih, Wc_hh, bc);
    kcopy<<<dim3(1024), B256, 0, stream>>>(h0, f, NQ * FEAT);   // h = f
    kzero<<<dim3(1024), B256, 0, stream>>>(cst, NQ * FEAT);     // c = 0

    // ---- Phase C: K=3 FCE iterations ----
    for (int it = 0; it < 3; ++it) {
        float* hc = (it & 1) ? h1 : h0;
        float* hx = (it & 1) ? h0 : h1;
        // r = softmax_col(hc @ G^T) @ G, slab by slab
        for (int sb = 0; sb < NS / SLAB; ++sb) {
            const float* Gs = G + (size_t)sb * SLAB * FEAT;
            gemm_abt<<<dim3(4, 64), B256, 0, stream>>>(hc, FEAT, Gs, FEAT, Pslab, SLAB, nullptr, FEAT);
            colstats_partial<<<dim3(2, 32), B256, 0, stream>>>(Pslab, pm, pz);
            colstats_combine<<<dim3(2), B256, 0, stream>>>(pm, pz, cm, ciz);
            exp_transform<<<dim3(1024), B256, 0, stream>>>(Pslab, cm, ciz);
            if (sb == 0) gemm_ab<0><<<dim3(8, 64), B256, 0, stream>>>(Pslab, SLAB, Gs, FEAT, r, FEAT, SLAB);
            else         gemm_ab<1><<<dim3(8, 64), B256, 0, stream>>>(Pslab, SLAB, Gs, FEAT, r, FEAT, SLAB);
        }
        // gates + cell, 4 k-slices of 128 (N=512 each), gslab aliases Pslab
        for (int sl = 0; sl < 4; ++sl) {
            gemm_gates<<<dim3(4, 64), B256, 0, stream>>>(f, r, hc,
                Wpack + (size_t)sl * 512 * 1536, Pslab, bpack + sl * 512);
            cell_slice<<<dim3(1024), B256, 0, stream>>>(Pslab, cst, hx, f, sl * 128);
        }
    }

    // ---- Phase D: out = log(softmax_col(h @ Gn^T) @ Y), slab by slab ----
    for (int sb = 0; sb < NS / SLAB; ++sb) {
        const float* Gs = Gn + (size_t)sb * SLAB * FEAT;
        gemm_abt<<<dim3(4, 64), B256, 0, stream>>>(h1, FEAT, Gs, FEAT, Pslab, SLAB, nullptr, FEAT);
        colstats_partial<<<dim3(2, 32), B256, 0, stream>>>(Pslab, pm, pz);
        colstats_combine<<<dim3(2), B256, 0, stream>>>(pm, pz, cm, ciz);
        exp_transform<<<dim3(1024), B256, 0, stream>>>(Pslab, cm, ciz);
        if (sb == 0) gemm_ab<0><<<dim3(1, 64), B256, 0, stream>>>(Pslab, SLAB, Y + (size_t)sb * SLAB * NC, NC, out, NC, SLAB);
        else         gemm_ab<1><<<dim3(1, 64), B256, 0, stream>>>(Pslab, SLAB, Y + (size_t)sb * SLAB * NC, NC, out, NC, SLAB);
    }
    klog<<<dim3(512), B256, 0, stream>>>(out, NQ * NC);
}

// Round 6
// 18891.484 us; speedup vs baseline: 1.9647x; 1.1969x over previous
//
#include <hip/hip_runtime.h>
#include <math.h>

#define FEAT 512
#define NS   4096
#define NQ   8192
#define NC   64
#define G4   2048   // 4*FEAT
#define SLAB 512    // support-slab width for column softmax
#define SENT 1.0e30f

using bf16x8 = __attribute__((ext_vector_type(8))) short;
using f32x4  = __attribute__((ext_vector_type(4))) float;

__device__ __forceinline__ float sigf(float x) { return 1.0f / (1.0f + expf(-x)); }

// RNE f32 -> bf16 hi, residual -> bf16 lo
__device__ __forceinline__ void split_bf16(float x, unsigned short& hi, unsigned short& lo) {
    unsigned u = __float_as_uint(x);
    unsigned r = u + 0x7FFFu + ((u >> 16) & 1u);
    hi = (unsigned short)(r >> 16);
    float res = x - __uint_as_float((unsigned)hi << 16);
    unsigned u2 = __float_as_uint(res);
    unsigned r2 = u2 + 0x7FFFu + ((u2 >> 16) & 1u);
    lo = (unsigned short)(r2 >> 16);
}

// ---------------- small utility kernels ----------------
__global__ void kcopy(float* __restrict__ dst, const float* __restrict__ src, int n) {
    int i = blockIdx.x * blockDim.x + threadIdx.x;
    int st = gridDim.x * blockDim.x;
    for (; i < n; i += st) dst[i] = src[i];
}

__global__ void kzero(float* __restrict__ dst, int n) {
    int i = blockIdx.x * blockDim.x + threadIdx.x;
    int st = gridDim.x * blockDim.x;
    for (; i < n; i += st) dst[i] = 0.0f;
}

__global__ void kfill(float* __restrict__ dst, float v, int n) {
    int i = blockIdx.x * blockDim.x + threadIdx.x;
    int st = gridDim.x * blockDim.x;
    for (; i < n; i += st) dst[i] = v;
}

__global__ void klog(float* __restrict__ o, int n) {
    int i = blockIdx.x * blockDim.x + threadIdx.x;
    int st = gridDim.x * blockDim.x;
    for (; i < n; i += st) o[i] = logf(o[i]);
}

// pack Wpack[k*4+g][0:1536] = [Wc_ih[g*512+k][0:1024] | Wc_hh[g*512+k][0:512]]
__global__ void pack_w(float* __restrict__ Wpack, float* __restrict__ bpack,
                       const float* __restrict__ Wc_ih, const float* __restrict__ Wc_hh,
                       const float* __restrict__ bc) {
    int i = blockIdx.x * blockDim.x + threadIdx.x;
    int st = gridDim.x * blockDim.x;
    const int n = G4 * 1536;
    for (; i < n; i += st) {
        int R = i / 1536, j = i - R * 1536;
        int k = R >> 2, g = R & 3;
        int row2 = g * FEAT + k;
        Wpack[i] = (j < 1024) ? Wc_ih[(size_t)row2 * 1024 + j]
                              : Wc_hh[(size_t)row2 * FEAT + (j - 1024)];
        if (j == 0) bpack[R] = bc[row2];
    }
}

// ================= MFMA split-bf16 GEMM: C = A @ B^T (+bias) =================
// A [M x K] f32, B [N x K] f32 (row-major, K contiguous on both).
// M,N multiples of 128, K of 32. TRISRC: A = [A0|A1|A2] concat along K (512 each).
template<int BIAS, int TRISRC>
__global__ __launch_bounds__(256)
void mm_abt(const float* __restrict__ A0, const float* __restrict__ A1,
            const float* __restrict__ A2, const float* __restrict__ B,
            int lda, int ldb, float* __restrict__ C, int ldc,
            const float* __restrict__ bias, int K)
{
    __shared__ unsigned short Ah[128][40], Al[128][40], Bh[128][40], Bl[128][40];
    const int tid = threadIdx.x;
    const int row0 = blockIdx.y * 128, col0 = blockIdx.x * 128;
    const int l = tid & 63;
    const int wm = ((tid >> 6) >> 1) * 64, wn = ((tid >> 6) & 1) * 64;
    const int fr = l & 15, fk = (l >> 4) * 8;

    f32x4 acc[4][4];
#pragma unroll
    for (int mt = 0; mt < 4; ++mt)
#pragma unroll
        for (int nt = 0; nt < 4; ++nt) acc[mt][nt] = (f32x4){0.f, 0.f, 0.f, 0.f};

    for (int k0 = 0; k0 < K; k0 += 32) {
        // ---- A tile stage (128x32 f32 -> hi/lo bf16) ----
#pragma unroll
        for (int p = 0; p < 4; ++p) {
            int flat = p * 256 + tid;
            int ar = flat >> 3, aq = (flat & 7) * 4;
            int gk = k0 + aq;
            const float* src;
            if (TRISRC) {
                int row = row0 + ar;
                src = (gk < 512)  ? (A0 + (size_t)row * FEAT + gk)
                    : (gk < 1024) ? (A1 + (size_t)row * FEAT + (gk - 512))
                                  : (A2 + (size_t)row * FEAT + (gk - 1024));
            } else {
                src = A0 + (size_t)(row0 + ar) * lda + gk;
            }
            float4 v = *(const float4*)src;
            unsigned short h0,h1,h2,h3,q0,q1,q2,q3;
            split_bf16(v.x, h0, q0); split_bf16(v.y, h1, q1);
            split_bf16(v.z, h2, q2); split_bf16(v.w, h3, q3);
            *(short4*)&Ah[ar][aq] = make_short4((short)h0,(short)h1,(short)h2,(short)h3);
            *(short4*)&Al[ar][aq] = make_short4((short)q0,(short)q1,(short)q2,(short)q3);
        }
        // ---- B tile stage (128 rows of B, K contiguous) ----
#pragma unroll
        for (int p = 0; p < 4; ++p) {
            int flat = p * 256 + tid;
            int br = flat >> 3, bq = (flat & 7) * 4;
            float4 v = *(const float4*)(B + (size_t)(col0 + br) * ldb + k0 + bq);
            unsigned short h0,h1,h2,h3,q0,q1,q2,q3;
            split_bf16(v.x, h0, q0); split_bf16(v.y, h1, q1);
            split_bf16(v.z, h2, q2); split_bf16(v.w, h3, q3);
            *(short4*)&Bh[br][bq] = make_short4((short)h0,(short)h1,(short)h2,(short)h3);
            *(short4*)&Bl[br][bq] = make_short4((short)q0,(short)q1,(short)q2,(short)q3);
        }
        __syncthreads();

        bf16x8 ah[4], al4[4], bh[4], bl4[4];
#pragma unroll
        for (int mt = 0; mt < 4; ++mt) {
            ah[mt]  = *(const bf16x8*)&Ah[wm + mt * 16 + fr][fk];
            al4[mt] = *(const bf16x8*)&Al[wm + mt * 16 + fr][fk];
        }
#pragma unroll
        for (int nt = 0; nt < 4; ++nt) {
            bh[nt]  = *(const bf16x8*)&Bh[wn + nt * 16 + fr][fk];
            bl4[nt] = *(const bf16x8*)&Bl[wn + nt * 16 + fr][fk];
        }
#pragma unroll
        for (int mt = 0; mt < 4; ++mt)
#pragma unroll
            for (int nt = 0; nt < 4; ++nt) {
                acc[mt][nt] = __builtin_amdgcn_mfma_f32_16x16x32_bf16(ah[mt],  bh[nt],  acc[mt][nt], 0, 0, 0);
                acc[mt][nt] = __builtin_amdgcn_mfma_f32_16x16x32_bf16(al4[mt], bh[nt],  acc[mt][nt], 0, 0, 0);
                acc[mt][nt] = __builtin_amdgcn_mfma_f32_16x16x32_bf16(ah[mt],  bl4[nt], acc[mt][nt], 0, 0, 0);
            }
        __syncthreads();
    }
    // ---- epilogue: C/D layout col=lane&15, row=(lane>>4)*4+j ----
#pragma unroll
    for (int mt = 0; mt < 4; ++mt) {
        int row = row0 + wm + mt * 16 + (l >> 4) * 4;
#pragma unroll
        for (int nt = 0; nt < 4; ++nt) {
            int col = col0 + wn + nt * 16 + fr;
            float bv = BIAS ? bias[col] : 0.0f;
#pragma unroll
            for (int j = 0; j < 4; ++j)
                C[(size_t)(row + j) * ldc + col] = acc[mt][nt][j] + bv;
        }
    }
}

// ================= MFMA split-bf16 GEMM: C (+)= A @ B =================
// A [M x K] f32, B [K x N] f32. M,N multiples of 128, K of 32.
template<int ACC>
__global__ __launch_bounds__(256)
void mm_ab(const float* __restrict__ A, int lda, const float* __restrict__ B,
           int ldb, float* __restrict__ C, int ldc, int K)
{
    __shared__ unsigned short Ah[128][40], Al[128][40], Bh[128][40], Bl[128][40];
    const int tid = threadIdx.x;
    const int row0 = blockIdx.y * 128, col0 = blockIdx.x * 128;
    const int l = tid & 63;
    const int wm = ((tid >> 6) >> 1) * 64, wn = ((tid >> 6) & 1) * 64;
    const int fr = l & 15, fk = (l >> 4) * 8;

    f32x4 acc[4][4];
#pragma unroll
    for (int mt = 0; mt < 4; ++mt)
#pragma unroll
        for (int nt = 0; nt < 4; ++nt) acc[mt][nt] = (f32x4){0.f, 0.f, 0.f, 0.f};

    for (int k0 = 0; k0 < K; k0 += 32) {
        // ---- A tile stage ----
#pragma unroll
        for (int p = 0; p < 4; ++p) {
            int flat = p * 256 + tid;
            int ar = flat >> 3, aq = (flat & 7) * 4;
            float4 v = *(const float4*)(A + (size_t)(row0 + ar) * lda + k0 + aq);
            unsigned short h0,h1,h2,h3,q0,q1,q2,q3;
            split_bf16(v.x, h0, q0); split_bf16(v.y, h1, q1);
            split_bf16(v.z, h2, q2); split_bf16(v.w, h3, q3);
            *(short4*)&Ah[ar][aq] = make_short4((short)h0,(short)h1,(short)h2,(short)h3);
            *(short4*)&Al[ar][aq] = make_short4((short)q0,(short)q1,(short)q2,(short)q3);
        }
        // ---- B tile stage: B[k][n] -> LDS [col][k], k-pairs packed as u32 ----
#pragma unroll
        for (int it = 0; it < 2; ++it) {
            int item = it * 256 + tid;        // 512 items
            int q  = item >> 4;               // col quad 0..31
            int kp = item & 15;               // k-pair 0..15
            const float* s0 = B + (size_t)(k0 + 2 * kp) * ldb + col0 + q * 4;
            float4 v0 = *(const float4*)s0;
            float4 v1 = *(const float4*)(s0 + ldb);
            float a0[4] = {v0.x, v0.y, v0.z, v0.w};
            float a1[4] = {v1.x, v1.y, v1.z, v1.w};
#pragma unroll
            for (int cc = 0; cc < 4; ++cc) {
                unsigned short h0, q0, h1, q1;
                split_bf16(a0[cc], h0, q0);
                split_bf16(a1[cc], h1, q1);
                int col = q * 4 + cc;
                *(unsigned*)&Bh[col][2 * kp] = (unsigned)h0 | ((unsigned)h1 << 16);
                *(unsigned*)&Bl[col][2 * kp] = (unsigned)q0 | ((unsigned)q1 << 16);
            }
        }
        __syncthreads();

        bf16x8 ah[4], al4[4], bh[4], bl4[4];
#pragma unroll
        for (int mt = 0; mt < 4; ++mt) {
            ah[mt]  = *(const bf16x8*)&Ah[wm + mt * 16 + fr][fk];
            al4[mt] = *(const bf16x8*)&Al[wm + mt * 16 + fr][fk];
        }
#pragma unroll
        for (int nt = 0; nt < 4; ++nt) {
            bh[nt]  = *(const bf16x8*)&Bh[wn + nt * 16 + fr][fk];
            bl4[nt] = *(const bf16x8*)&Bl[wn + nt * 16 + fr][fk];
        }
#pragma unroll
        for (int mt = 0; mt < 4; ++mt)
#pragma unroll
            for (int nt = 0; nt < 4; ++nt) {
                acc[mt][nt] = __builtin_amdgcn_mfma_f32_16x16x32_bf16(ah[mt],  bh[nt],  acc[mt][nt], 0, 0, 0);
                acc[mt][nt] = __builtin_amdgcn_mfma_f32_16x16x32_bf16(al4[mt], bh[nt],  acc[mt][nt], 0, 0, 0);
                acc[mt][nt] = __builtin_amdgcn_mfma_f32_16x16x32_bf16(ah[mt],  bl4[nt], acc[mt][nt], 0, 0, 0);
            }
        __syncthreads();
    }
#pragma unroll
    for (int mt = 0; mt < 4; ++mt) {
        int row = row0 + wm + mt * 16 + (l >> 4) * 4;
#pragma unroll
        for (int nt = 0; nt < 4; ++nt) {
            int col = col0 + wn + nt * 16 + fr;
#pragma unroll
            for (int j = 0; j < 4; ++j) {
                size_t idx = (size_t)(row + j) * ldc + col;
                if (ACC) C[idx] += acc[mt][nt][j];
                else     C[idx]  = acc[mt][nt][j];
            }
        }
    }
}

// ---------------- f32 GEMM: C (+)= A @ B (only for the tiny N=64 Y-GEMM) ----------------
template<int ACC>
__global__ __launch_bounds__(256)
void gemm_ab(const float* __restrict__ A, int lda,
             const float* __restrict__ B, int ldb,
             float* __restrict__ C, int ldc, int K)
{
    __shared__ float As[16][128];
    __shared__ float Bs[16][64];
    const int row0 = blockIdx.y * 128;
    const int col0 = blockIdx.x * 64;
    const int tid = threadIdx.x;
    const int tr = tid >> 4, tc = tid & 15;
    float acc[8][4];
#pragma unroll
    for (int i = 0; i < 8; ++i)
#pragma unroll
        for (int j = 0; j < 4; ++j) acc[i][j] = 0.0f;

    for (int k0 = 0; k0 < K; k0 += 16) {
#pragma unroll
        for (int p = tid; p < 512; p += 256) {
            int r = p >> 2, kq = (p & 3) * 4;
            float4 av = *(const float4*)(A + (size_t)(row0 + r) * lda + k0 + kq);
            As[kq + 0][r] = av.x; As[kq + 1][r] = av.y; As[kq + 2][r] = av.z; As[kq + 3][r] = av.w;
        }
        {
            int kr = tid >> 4, cq = (tid & 15) * 4;
            float4 bv = *(const float4*)(B + (size_t)(k0 + kr) * ldb + col0 + cq);
            *(float4*)&Bs[kr][cq] = bv;
        }
        __syncthreads();
#pragma unroll
        for (int kk = 0; kk < 16; ++kk) {
            float4 a0 = *(const float4*)&As[kk][tr * 8];
            float4 a1 = *(const float4*)&As[kk][tr * 8 + 4];
            float4 b0 = *(const float4*)&Bs[kk][tc * 4];
            float a[8] = {a0.x, a0.y, a0.z, a0.w, a1.x, a1.y, a1.z, a1.w};
            float b[4] = {b0.x, b0.y, b0.z, b0.w};
#pragma unroll
            for (int i = 0; i < 8; ++i)
#pragma unroll
                for (int j = 0; j < 4; ++j) acc[i][j] += a[i] * b[j];
        }
        __syncthreads();
    }
#pragma unroll
    for (int i = 0; i < 8; ++i) {
        size_t idx = (size_t)(row0 + tr * 8 + i) * ldc + col0 + tc * 4;
#pragma unroll
        for (int j = 0; j < 4; ++j) {
            if (ACC) C[idx + j] += acc[i][j];
            else     C[idx + j]  = acc[i][j];
        }
    }
}

// ---------------- persistent bidirectional LSTM (sentinel data-polling) ----------------
__global__ __launch_bounds__(256, 1)
void lstm_persist(const float* __restrict__ Xf, const float* __restrict__ Xb,
                  const float* __restrict__ Wf, const float* __restrict__ Wb,
                  float* __restrict__ Hf, float* __restrict__ Hb)
{
    __shared__ float hs[FEAT];

    const int bid = blockIdx.x;
    const int dir = bid >> 5;
    const int blk = bid & 31;
    const int tid = threadIdx.x;
    const float* W = dir ? Wb : Wf;
    const float* X = dir ? Xb : Xf;
    float* H = dir ? Hb : Hf;

    const int e = tid >> 4, l = tid & 15;
    const int hidx = blk * 16 + e;

    float4 wr[32];
#pragma unroll
    for (int g = 0; g < 4; ++g)
#pragma unroll
        for (int j = 0; j < 8; ++j)
            wr[g * 8 + j] = *(const float4*)(W + (size_t)(g * FEAT + hidx) * FEAT + l * 4 + j * 64);

    float c_reg = 0.0f;

    for (int t = 0; t < NS; ++t) {
        const int trow = dir ? (NS - 1 - t) : t;
        const float* Xrow = X + (size_t)trow * G4;
        float x0 = 0.f, x1 = 0.f, x2 = 0.f, x3 = 0.f;
        if (l == 0) {
            x0 = Xrow[hidx];            x1 = Xrow[FEAT + hidx];
            x2 = Xrow[2 * FEAT + hidx]; x3 = Xrow[3 * FEAT + hidx];
        }
        if (t > 0) {
            const int prow = dir ? (trow + 1) : (trow - 1);
            const float* Hp = H + (size_t)prow * FEAT;
            float v0, v1;
            do { v0 = __hip_atomic_load(Hp + tid, __ATOMIC_RELAXED,
                                        __HIP_MEMORY_SCOPE_AGENT); } while (v0 == SENT);
            do { v1 = __hip_atomic_load(Hp + tid + 256, __ATOMIC_RELAXED,
                                        __HIP_MEMORY_SCOPE_AGENT); } while (v1 == SENT);
            hs[tid] = v0; hs[tid + 256] = v1;
        } else {
            hs[tid] = 0.0f; hs[tid + 256] = 0.0f;
        }
        __syncthreads();

        float4 hv4[8];
#pragma unroll
        for (int j = 0; j < 8; ++j) hv4[j] = *(const float4*)&hs[l * 4 + j * 64];

        float dots[4];
#pragma unroll
        for (int g = 0; g < 4; ++g) {
            float s = 0.0f;
#pragma unroll
            for (int j = 0; j < 8; ++j) {
                float4 w4 = wr[g * 8 + j];
                float4 h4 = hv4[j];
                s += w4.x * h4.x + w4.y * h4.y + w4.z * h4.z + w4.w * h4.w;
            }
#pragma unroll
            for (int off = 8; off >= 1; off >>= 1) s += __shfl_xor(s, off, 64);
            dots[g] = s;
        }
        if (l == 0) {
            float gi = dots[0] + x0, gf = dots[1] + x1;
            float gg = dots[2] + x2, go = dots[3] + x3;
            float cn = sigf(gf) * c_reg + sigf(gi) * tanhf(gg);
            float hv = sigf(go) * tanhf(cn);
            c_reg = cn;
            __hip_atomic_store(H + (size_t)trow * FEAT + hidx, hv,
                               __ATOMIC_RELAXED, __HIP_MEMORY_SCOPE_AGENT);
        }
        __syncthreads();
    }
}

// ---------------- fused G assembly + row-normalize ----------------
__global__ __launch_bounds__(256)
void gnorm_fuse(const float* __restrict__ S, const float* __restrict__ Hf,
                const float* __restrict__ Hb, float* __restrict__ G,
                float* __restrict__ Gn)
{
    const int row = blockIdx.x;
    const size_t base = (size_t)row * FEAT;
    const int tid = threadIdx.x;
    float v0 = S[base + tid]       + Hf[base + tid]       + Hb[base + tid];
    float v1 = S[base + tid + 256] + Hf[base + tid + 256] + Hb[base + tid + 256];
    G[base + tid] = v0;
    G[base + tid + 256] = v1;
    float s = v0 * v0 + v1 * v1;
#pragma unroll
    for (int off = 32; off >= 1; off >>= 1) s += __shfl_xor(s, off, 64);
    __shared__ float red[4];
    if ((tid & 63) == 0) red[tid >> 6] = s;
    __syncthreads();
    float tot = red[0] + red[1] + red[2] + red[3];
    float inv = 1.0f / (sqrtf(tot) + 1e-5f);
    Gn[base + tid] = v0 * inv;
    Gn[base + tid + 256] = v1 * inv;
}

// ---------------- column softmax stats over a [NQ x SLAB] slab ----------------
__global__ __launch_bounds__(256)
void colstats_partial(const float* __restrict__ A, float* __restrict__ pm,
                      float* __restrict__ pz)
{
    const int col = blockIdx.x * 256 + threadIdx.x;
    const int r0 = blockIdx.y * 256;
    float m = -3.0e38f, z = 0.0f;
    for (int r = 0; r < 256; ++r) {
        float v = A[(size_t)(r0 + r) * SLAB + col];
        if (v > m) { z = z * expf(m - v) + 1.0f; m = v; }
        else       { z += expf(v - m); }
    }
    pm[(size_t)blockIdx.y * SLAB + col] = m;
    pz[(size_t)blockIdx.y * SLAB + col] = z;
}

__global__ __launch_bounds__(256)
void colstats_combine(const float* __restrict__ pm, const float* __restrict__ pz,
                      float* __restrict__ cm, float* __restrict__ ciz)
{
    const int col = blockIdx.x * 256 + threadIdx.x;
    float m = -3.0e38f;
    for (int p = 0; p < 32; ++p) m = fmaxf(m, pm[(size_t)p * SLAB + col]);
    float z = 0.0f;
    for (int p = 0; p < 32; ++p) z += pz[(size_t)p * SLAB + col] * expf(pm[(size_t)p * SLAB + col] - m);
    cm[col] = m;
    ciz[col] = 1.0f / z;
}

__global__ void exp_transform(float* __restrict__ A, const float* __restrict__ cm,
                              const float* __restrict__ ciz)
{
    int i = blockIdx.x * blockDim.x + threadIdx.x;
    const int st = gridDim.x * blockDim.x;
    const int n = NQ * SLAB;
    for (; i < n; i += st) {
        int col = i & (SLAB - 1);
        A[i] = expf(A[i] - cm[col]) * ciz[col];
    }
}

// ---------------- FCE cell on one k-slice of 128 ----------------
__global__ void cell_slice(const float* __restrict__ gslab, float* __restrict__ cst,
                           float* __restrict__ hnext, const float* __restrict__ f,
                           int k0)
{
    int i = blockIdx.x * blockDim.x + threadIdx.x;
    const int st = gridDim.x * blockDim.x;
    const int n = NQ * 128;
    for (; i < n; i += st) {
        int q = i >> 7, kk = i & 127;
        float4 g = *(const float4*)(gslab + (size_t)q * 512 + kk * 4);
        int idx = q * FEAT + k0 + kk;
        float cold = cst[idx];
        float cn = sigf(g.y) * cold + sigf(g.x) * tanhf(g.z);
        float hn = sigf(g.w) * tanhf(cn) + f[idx];
        cst[idx] = cn;
        hnext[idx] = hn;
    }
}

// ---------------- launch ----------------
extern "C" void kernel_launch(void* const* d_in, const int* in_sizes, int n_in,
                              void* d_out, int out_size, void* d_ws, size_t ws_size,
                              hipStream_t stream)
{
    (void)in_sizes; (void)n_in; (void)out_size; (void)ws_size;
    const float* S     = (const float*)d_in[0];
    const float* f     = (const float*)d_in[1];
    const float* Y     = (const float*)d_in[2];
    const float* Wf_ih = (const float*)d_in[3];
    const float* Wf_hh = (const float*)d_in[4];
    const float* bf    = (const float*)d_in[5];
    const float* Wb_ih = (const float*)d_in[6];
    const float* Wb_hh = (const float*)d_in[7];
    const float* bb    = (const float*)d_in[8];
    const float* Wc_ih = (const float*)d_in[9];
    const float* Wc_hh = (const float*)d_in[10];
    const float* bc    = (const float*)d_in[11];
    float* out = (float*)d_out;

    float* ws = (float*)d_ws;
    // region 0: 16M floats, phase A/B = Xf|Xb ; phase C = r|h0|h1|cst
    float* Xf   = ws;                       // 8M
    float* Xb   = ws + (size_t)8 * 1024 * 1024;
    float* r    = ws;                       // 4M each
    float* h0   = ws + (size_t)4 * 1024 * 1024;
    float* h1   = ws + (size_t)8 * 1024 * 1024;
    float* cst  = ws + (size_t)12 * 1024 * 1024;
    size_t off  = (size_t)16 * 1024 * 1024;
    auto alloc = [&](size_t n) { float* p = ws + off; off += n; return p; };
    float* Pslab = alloc((size_t)NQ * SLAB);   // 4M (gslab; also Hf|Hb during LSTM)
    float* G     = alloc((size_t)NS * FEAT);   // 2M
    float* Gn    = alloc((size_t)NS * FEAT);   // 2M
    float* Wpack = alloc((size_t)G4 * 1536);   // 3M
    float* bpack = alloc(G4);
    float* pm    = alloc((size_t)32 * SLAB);
    float* pz    = alloc((size_t)32 * SLAB);
    float* cm    = alloc(SLAB);
    float* ciz   = alloc(SLAB);

    float* Hf = Pslab;
    float* Hb = Pslab + (size_t)2 * 1024 * 1024;

    const dim3 B256(256);

    // ---- Phase A: Xf = S@Wf_ih^T+bf, Xb = S@Wb_ih^T+bb (MFMA) ----
    mm_abt<1,0><<<dim3(16, 32), B256, 0, stream>>>(S, nullptr, nullptr, Wf_ih, FEAT, FEAT, Xf, G4, bf, FEAT);
    mm_abt<1,0><<<dim3(16, 32), B256, 0, stream>>>(S, nullptr, nullptr, Wb_ih, FEAT, FEAT, Xb, G4, bb, FEAT);

    // ---- Phase B: persistent bidirectional LSTM ----
    kfill<<<dim3(2048), B256, 0, stream>>>(Pslab, SENT, 4 * 1024 * 1024);  // Hf+Hb sentinel
    lstm_persist<<<dim3(64), B256, 0, stream>>>(Xf, Xb, Wf_hh, Wb_hh, Hf, Hb);
    gnorm_fuse<<<dim3(NS), B256, 0, stream>>>(S, Hf, Hb, G, Gn);

    // ---- Phase C prep ----
    pack_w<<<dim3(2048), B256, 0, stream>>>(Wpack, bpack, Wc_ih, Wc_hh, bc);
    kcopy<<<dim3(1024), B256, 0, stream>>>(h0, f, NQ * FEAT);   // h = f
    kzero<<<dim3(1024), B256, 0, stream>>>(cst, NQ * FEAT);     // c = 0

    // ---- Phase C: K=3 FCE iterations ----
    for (int it = 0; it < 3; ++it) {
        float* hc = (it & 1) ? h1 : h0;
        float* hx = (it & 1) ? h0 : h1;
        for (int sb = 0; sb < NS / SLAB; ++sb) {
            const float* Gs = G + (size_t)sb * SLAB * FEAT;
            mm_abt<0,0><<<dim3(4, 64), B256, 0, stream>>>(hc, nullptr, nullptr, Gs, FEAT, FEAT, Pslab, SLAB, nullptr, FEAT);
            colstats_partial<<<dim3(2, 32), B256, 0, stream>>>(Pslab, pm, pz);
            colstats_combine<<<dim3(2), B256, 0, stream>>>(pm, pz, cm, ciz);
            exp_transform<<<dim3(1024), B256, 0, stream>>>(Pslab, cm, ciz);
            if (sb == 0) mm_ab<0><<<dim3(4, 64), B256, 0, stream>>>(Pslab, SLAB, Gs, FEAT, r, FEAT, SLAB);
            else         mm_ab<1><<<dim3(4, 64), B256, 0, stream>>>(Pslab, SLAB, Gs, FEAT, r, FEAT, SLAB);
        }
        for (int sl = 0; sl < 4; ++sl) {
            mm_abt<1,1><<<dim3(4, 64), B256, 0, stream>>>(f, r, hc,
                Wpack + (size_t)sl * 512 * 1536, FEAT, 1536, Pslab, 512, bpack + sl * 512, 1536);
            cell_slice<<<dim3(1024), B256, 0, stream>>>(Pslab, cst, hx, f, sl * 128);
        }
    }

    // ---- Phase D: out = log(softmax_col(h @ Gn^T) @ Y), slab by slab ----
    for (int sb = 0; sb < NS / SLAB; ++sb) {
        const float* Gs = Gn + (size_t)sb * SLAB * FEAT;
        mm_abt<0,0><<<dim3(4, 64), B256, 0, stream>>>(h1, nullptr, nullptr, Gs, FEAT, FEAT, Pslab, SLAB, nullptr, FEAT);
        colstats_partial<<<dim3(2, 32), B256, 0, stream>>>(Pslab, pm, pz);
        colstats_combine<<<dim3(2), B256, 0, stream>>>(pm, pz, cm, ciz);
        exp_transform<<<dim3(1024), B256, 0, stream>>>(Pslab, cm, ciz);
        if (sb == 0) gemm_ab<0><<<dim3(1, 64), B256, 0, stream>>>(Pslab, SLAB, Y + (size_t)sb * SLAB * NC, NC, out, NC, SLAB);
        else         gemm_ab<1><<<dim3(1, 64), B256, 0, stream>>>(Pslab, SLAB, Y + (size_t)sb * SLAB * NC, NC, out, NC, SLAB);
    }
    klog<<<dim3(512), B256, 0, stream>>>(out, NQ * NC);
}

// Round 7
// 15577.393 us; speedup vs baseline: 2.3827x; 1.2128x over previous
//
#include <hip/hip_runtime.h>
#include <math.h>

#define FEAT 512
#define NS   4096
#define NQ   8192
#define NC   64
#define G4   2048   // 4*FEAT
#define SLAB 512    // support-slab width for column softmax
#define SENT 1.0e30f

using bf16x8 = __attribute__((ext_vector_type(8))) short;
using f32x4  = __attribute__((ext_vector_type(4))) float;

__device__ __forceinline__ float sigf(float x) { return 1.0f / (1.0f + expf(-x)); }

// RNE f32 -> bf16 hi, residual -> bf16 lo
__device__ __forceinline__ void split_bf16(float x, unsigned short& hi, unsigned short& lo) {
    unsigned u = __float_as_uint(x);
    unsigned r = u + 0x7FFFu + ((u >> 16) & 1u);
    hi = (unsigned short)(r >> 16);
    float res = x - __uint_as_float((unsigned)hi << 16);
    unsigned u2 = __float_as_uint(res);
    unsigned r2 = u2 + 0x7FFFu + ((u2 >> 16) & 1u);
    lo = (unsigned short)(r2 >> 16);
}

// ---------------- small utility kernels ----------------
__global__ void kcopy(float* __restrict__ dst, const float* __restrict__ src, int n) {
    int i = blockIdx.x * blockDim.x + threadIdx.x;
    int st = gridDim.x * blockDim.x;
    for (; i < n; i += st) dst[i] = src[i];
}

__global__ void kzero(float* __restrict__ dst, int n) {
    int i = blockIdx.x * blockDim.x + threadIdx.x;
    int st = gridDim.x * blockDim.x;
    for (; i < n; i += st) dst[i] = 0.0f;
}

__global__ void kfill(float* __restrict__ dst, float v, int n) {
    int i = blockIdx.x * blockDim.x + threadIdx.x;
    int st = gridDim.x * blockDim.x;
    for (; i < n; i += st) dst[i] = v;
}

__global__ void klog(float* __restrict__ o, int n) {
    int i = blockIdx.x * blockDim.x + threadIdx.x;
    int st = gridDim.x * blockDim.x;
    for (; i < n; i += st) o[i] = logf(o[i]);
}

// pack Wpack[k*4+g][0:1536] = [Wc_ih[g*512+k][0:1024] | Wc_hh[g*512+k][0:512]]
__global__ void pack_w(float* __restrict__ Wpack, float* __restrict__ bpack,
                       const float* __restrict__ Wc_ih, const float* __restrict__ Wc_hh,
                       const float* __restrict__ bc) {
    int i = blockIdx.x * blockDim.x + threadIdx.x;
    int st = gridDim.x * blockDim.x;
    const int n = G4 * 1536;
    for (; i < n; i += st) {
        int R = i / 1536, j = i - R * 1536;
        int k = R >> 2, g = R & 3;
        int row2 = g * FEAT + k;
        Wpack[i] = (j < 1024) ? Wc_ih[(size_t)row2 * 1024 + j]
                              : Wc_hh[(size_t)row2 * FEAT + (j - 1024)];
        if (j == 0) bpack[R] = bc[row2];
    }
}

// ================= MFMA split-bf16 GEMM: C = A @ B^T (+bias) =================
// A [M x K] f32, B [N x K] f32 (row-major, K contiguous on both).
// M,N multiples of 128, K of 32. TRISRC: A = [A0|A1|A2] concat along K (512 each).
template<int BIAS, int TRISRC>
__global__ __launch_bounds__(256)
void mm_abt(const float* __restrict__ A0, const float* __restrict__ A1,
            const float* __restrict__ A2, const float* __restrict__ B,
            int lda, int ldb, float* __restrict__ C, int ldc,
            const float* __restrict__ bias, int K)
{
    __shared__ unsigned short Ah[128][40], Al[128][40], Bh[128][40], Bl[128][40];
    const int tid = threadIdx.x;
    const int row0 = blockIdx.y * 128, col0 = blockIdx.x * 128;
    const int l = tid & 63;
    const int wm = ((tid >> 6) >> 1) * 64, wn = ((tid >> 6) & 1) * 64;
    const int fr = l & 15, fk = (l >> 4) * 8;

    f32x4 acc[4][4];
#pragma unroll
    for (int mt = 0; mt < 4; ++mt)
#pragma unroll
        for (int nt = 0; nt < 4; ++nt) acc[mt][nt] = (f32x4){0.f, 0.f, 0.f, 0.f};

    for (int k0 = 0; k0 < K; k0 += 32) {
#pragma unroll
        for (int p = 0; p < 4; ++p) {
            int flat = p * 256 + tid;
            int ar = flat >> 3, aq = (flat & 7) * 4;
            int gk = k0 + aq;
            const float* src;
            if (TRISRC) {
                int row = row0 + ar;
                src = (gk < 512)  ? (A0 + (size_t)row * FEAT + gk)
                    : (gk < 1024) ? (A1 + (size_t)row * FEAT + (gk - 512))
                                  : (A2 + (size_t)row * FEAT + (gk - 1024));
            } else {
                src = A0 + (size_t)(row0 + ar) * lda + gk;
            }
            float4 v = *(const float4*)src;
            unsigned short h0,h1,h2,h3,q0,q1,q2,q3;
            split_bf16(v.x, h0, q0); split_bf16(v.y, h1, q1);
            split_bf16(v.z, h2, q2); split_bf16(v.w, h3, q3);
            *(short4*)&Ah[ar][aq] = make_short4((short)h0,(short)h1,(short)h2,(short)h3);
            *(short4*)&Al[ar][aq] = make_short4((short)q0,(short)q1,(short)q2,(short)q3);
        }
#pragma unroll
        for (int p = 0; p < 4; ++p) {
            int flat = p * 256 + tid;
            int br = flat >> 3, bq = (flat & 7) * 4;
            float4 v = *(const float4*)(B + (size_t)(col0 + br) * ldb + k0 + bq);
            unsigned short h0,h1,h2,h3,q0,q1,q2,q3;
            split_bf16(v.x, h0, q0); split_bf16(v.y, h1, q1);
            split_bf16(v.z, h2, q2); split_bf16(v.w, h3, q3);
            *(short4*)&Bh[br][bq] = make_short4((short)h0,(short)h1,(short)h2,(short)h3);
            *(short4*)&Bl[br][bq] = make_short4((short)q0,(short)q1,(short)q2,(short)q3);
        }
        __syncthreads();

        bf16x8 ah[4], al4[4], bh[4], bl4[4];
#pragma unroll
        for (int mt = 0; mt < 4; ++mt) {
            ah[mt]  = *(const bf16x8*)&Ah[wm + mt * 16 + fr][fk];
            al4[mt] = *(const bf16x8*)&Al[wm + mt * 16 + fr][fk];
        }
#pragma unroll
        for (int nt = 0; nt < 4; ++nt) {
            bh[nt]  = *(const bf16x8*)&Bh[wn + nt * 16 + fr][fk];
            bl4[nt] = *(const bf16x8*)&Bl[wn + nt * 16 + fr][fk];
        }
#pragma unroll
        for (int mt = 0; mt < 4; ++mt)
#pragma unroll
            for (int nt = 0; nt < 4; ++nt) {
                acc[mt][nt] = __builtin_amdgcn_mfma_f32_16x16x32_bf16(ah[mt],  bh[nt],  acc[mt][nt], 0, 0, 0);
                acc[mt][nt] = __builtin_amdgcn_mfma_f32_16x16x32_bf16(al4[mt], bh[nt],  acc[mt][nt], 0, 0, 0);
                acc[mt][nt] = __builtin_amdgcn_mfma_f32_16x16x32_bf16(ah[mt],  bl4[nt], acc[mt][nt], 0, 0, 0);
            }
        __syncthreads();
    }
#pragma unroll
    for (int mt = 0; mt < 4; ++mt) {
        int row = row0 + wm + mt * 16 + (l >> 4) * 4;
#pragma unroll
        for (int nt = 0; nt < 4; ++nt) {
            int col = col0 + wn + nt * 16 + fr;
            float bv = BIAS ? bias[col] : 0.0f;
#pragma unroll
            for (int j = 0; j < 4; ++j)
                C[(size_t)(row + j) * ldc + col] = acc[mt][nt][j] + bv;
        }
    }
}

// ================= MFMA split-bf16 GEMM: C (+)= A @ B =================
// EXP: A-values transformed exp(v - cm[k])*ciz[k] during staging (softmax fuse).
template<int ACC, int EXP>
__global__ __launch_bounds__(256)
void mm_ab(const float* __restrict__ A, int lda, const float* __restrict__ B,
           int ldb, float* __restrict__ C, int ldc, int K,
           const float* __restrict__ cm, const float* __restrict__ ciz)
{
    __shared__ unsigned short Ah[128][40], Al[128][40], Bh[128][40], Bl[128][40];
    const int tid = threadIdx.x;
    const int row0 = blockIdx.y * 128, col0 = blockIdx.x * 128;
    const int l = tid & 63;
    const int wm = ((tid >> 6) >> 1) * 64, wn = ((tid >> 6) & 1) * 64;
    const int fr = l & 15, fk = (l >> 4) * 8;

    f32x4 acc[4][4];
#pragma unroll
    for (int mt = 0; mt < 4; ++mt)
#pragma unroll
        for (int nt = 0; nt < 4; ++nt) acc[mt][nt] = (f32x4){0.f, 0.f, 0.f, 0.f};

    for (int k0 = 0; k0 < K; k0 += 32) {
#pragma unroll
        for (int p = 0; p < 4; ++p) {
            int flat = p * 256 + tid;
            int ar = flat >> 3, aq = (flat & 7) * 4;
            float4 v = *(const float4*)(A + (size_t)(row0 + ar) * lda + k0 + aq);
            if (EXP) {
                int kk = k0 + aq;
                v.x = expf(v.x - cm[kk + 0]) * ciz[kk + 0];
                v.y = expf(v.y - cm[kk + 1]) * ciz[kk + 1];
                v.z = expf(v.z - cm[kk + 2]) * ciz[kk + 2];
                v.w = expf(v.w - cm[kk + 3]) * ciz[kk + 3];
            }
            unsigned short h0,h1,h2,h3,q0,q1,q2,q3;
            split_bf16(v.x, h0, q0); split_bf16(v.y, h1, q1);
            split_bf16(v.z, h2, q2); split_bf16(v.w, h3, q3);
            *(short4*)&Ah[ar][aq] = make_short4((short)h0,(short)h1,(short)h2,(short)h3);
            *(short4*)&Al[ar][aq] = make_short4((short)q0,(short)q1,(short)q2,(short)q3);
        }
#pragma unroll
        for (int it = 0; it < 2; ++it) {
            int item = it * 256 + tid;        // 512 items
            int q  = item >> 4;               // col quad 0..31
            int kp = item & 15;               // k-pair 0..15
            const float* s0 = B + (size_t)(k0 + 2 * kp) * ldb + col0 + q * 4;
            float4 v0 = *(const float4*)s0;
            float4 v1 = *(const float4*)(s0 + ldb);
            float a0[4] = {v0.x, v0.y, v0.z, v0.w};
            float a1[4] = {v1.x, v1.y, v1.z, v1.w};
#pragma unroll
            for (int cc = 0; cc < 4; ++cc) {
                unsigned short h0, q0, h1, q1;
                split_bf16(a0[cc], h0, q0);
                split_bf16(a1[cc], h1, q1);
                int col = q * 4 + cc;
                *(unsigned*)&Bh[col][2 * kp] = (unsigned)h0 | ((unsigned)h1 << 16);
                *(unsigned*)&Bl[col][2 * kp] = (unsigned)q0 | ((unsigned)q1 << 16);
            }
        }
        __syncthreads();

        bf16x8 ah[4], al4[4], bh[4], bl4[4];
#pragma unroll
        for (int mt = 0; mt < 4; ++mt) {
            ah[mt]  = *(const bf16x8*)&Ah[wm + mt * 16 + fr][fk];
            al4[mt] = *(const bf16x8*)&Al[wm + mt * 16 + fr][fk];
        }
#pragma unroll
        for (int nt = 0; nt < 4; ++nt) {
            bh[nt]  = *(const bf16x8*)&Bh[wn + nt * 16 + fr][fk];
            bl4[nt] = *(const bf16x8*)&Bl[wn + nt * 16 + fr][fk];
        }
#pragma unroll
        for (int mt = 0; mt < 4; ++mt)
#pragma unroll
            for (int nt = 0; nt < 4; ++nt) {
                acc[mt][nt] = __builtin_amdgcn_mfma_f32_16x16x32_bf16(ah[mt],  bh[nt],  acc[mt][nt], 0, 0, 0);
                acc[mt][nt] = __builtin_amdgcn_mfma_f32_16x16x32_bf16(al4[mt], bh[nt],  acc[mt][nt], 0, 0, 0);
                acc[mt][nt] = __builtin_amdgcn_mfma_f32_16x16x32_bf16(ah[mt],  bl4[nt], acc[mt][nt], 0, 0, 0);
            }
        __syncthreads();
    }
#pragma unroll
    for (int mt = 0; mt < 4; ++mt) {
        int row = row0 + wm + mt * 16 + (l >> 4) * 4;
#pragma unroll
        for (int nt = 0; nt < 4; ++nt) {
            int col = col0 + wn + nt * 16 + fr;
#pragma unroll
            for (int j = 0; j < 4; ++j) {
                size_t idx = (size_t)(row + j) * ldc + col;
                if (ACC) C[idx] += acc[mt][nt][j];
                else     C[idx]  = acc[mt][nt][j];
            }
        }
    }
}

// ---------------- f32 GEMM: C (+)= A @ B (tiny N=64 Y-GEMM), optional exp fuse ----------------
template<int ACC, int EXP>
__global__ __launch_bounds__(256)
void gemm_ab(const float* __restrict__ A, int lda,
             const float* __restrict__ B, int ldb,
             float* __restrict__ C, int ldc, int K,
             const float* __restrict__ cm, const float* __restrict__ ciz)
{
    __shared__ float As[16][128];
    __shared__ float Bs[16][64];
    const int row0 = blockIdx.y * 128;
    const int col0 = blockIdx.x * 64;
    const int tid = threadIdx.x;
    const int tr = tid >> 4, tc = tid & 15;
    float acc[8][4];
#pragma unroll
    for (int i = 0; i < 8; ++i)
#pragma unroll
        for (int j = 0; j < 4; ++j) acc[i][j] = 0.0f;

    for (int k0 = 0; k0 < K; k0 += 16) {
#pragma unroll
        for (int p = tid; p < 512; p += 256) {
            int r = p >> 2, kq = (p & 3) * 4;
            float4 av = *(const float4*)(A + (size_t)(row0 + r) * lda + k0 + kq);
            if (EXP) {
                int kk = k0 + kq;
                av.x = expf(av.x - cm[kk + 0]) * ciz[kk + 0];
                av.y = expf(av.y - cm[kk + 1]) * ciz[kk + 1];
                av.z = expf(av.z - cm[kk + 2]) * ciz[kk + 2];
                av.w = expf(av.w - cm[kk + 3]) * ciz[kk + 3];
            }
            As[kq + 0][r] = av.x; As[kq + 1][r] = av.y; As[kq + 2][r] = av.z; As[kq + 3][r] = av.w;
        }
        {
            int kr = tid >> 4, cq = (tid & 15) * 4;
            float4 bv = *(const float4*)(B + (size_t)(k0 + kr) * ldb + col0 + cq);
            *(float4*)&Bs[kr][cq] = bv;
        }
        __syncthreads();
#pragma unroll
        for (int kk = 0; kk < 16; ++kk) {
            float4 a0 = *(const float4*)&As[kk][tr * 8];
            float4 a1 = *(const float4*)&As[kk][tr * 8 + 4];
            float4 b0 = *(const float4*)&Bs[kk][tc * 4];
            float a[8] = {a0.x, a0.y, a0.z, a0.w, a1.x, a1.y, a1.z, a1.w};
            float b[4] = {b0.x, b0.y, b0.z, b0.w};
#pragma unroll
            for (int i = 0; i < 8; ++i)
#pragma unroll
                for (int j = 0; j < 4; ++j) acc[i][j] += a[i] * b[j];
        }
        __syncthreads();
    }
#pragma unroll
    for (int i = 0; i < 8; ++i) {
        size_t idx = (size_t)(row0 + tr * 8 + i) * ldc + col0 + tc * 4;
#pragma unroll
        for (int j = 0; j < 4; ++j) {
            if (ACC) C[idx + j] += acc[i][j];
            else     C[idx + j]  = acc[i][j];
        }
    }
}

// ---------------- persistent bidirectional LSTM (sentinel data-polling) ----------------
// W_hh pinned in VGPRs (asm barrier defeats rematerialization), combined h-poll,
// single barrier/step via hs double-buffer.
__global__ __launch_bounds__(256, 1)
void lstm_persist(const float* __restrict__ Xf, const float* __restrict__ Xb,
                  const float* __restrict__ Wf, const float* __restrict__ Wb,
                  float* __restrict__ Hf, float* __restrict__ Hb)
{
    __shared__ float hs[2][FEAT];

    const int bid = blockIdx.x;
    const int dir = bid >> 5;
    const int blk = bid & 31;
    const int tid = threadIdx.x;
    const float* W = dir ? Wb : Wf;
    const float* X = dir ? Xb : Xf;
    float* H = dir ? Hb : Hf;

    const int e = tid >> 4, l = tid & 15;
    const int hidx = blk * 16 + e;

    float4 wr[32];
#pragma unroll
    for (int g = 0; g < 4; ++g)
#pragma unroll
        for (int j = 0; j < 8; ++j)
            wr[g * 8 + j] = *(const float4*)(W + (size_t)(g * FEAT + hidx) * FEAT + l * 4 + j * 64);
    // pin W in VGPRs: opaque to the compiler's load-rematerializer
#pragma unroll
    for (int i = 0; i < 32; ++i)
        asm volatile("" : "+v"(wr[i].x), "+v"(wr[i].y), "+v"(wr[i].z), "+v"(wr[i].w));

    float c_reg = 0.0f;

    for (int t = 0; t < NS; ++t) {
        const int trow = dir ? (NS - 1 - t) : t;
        const float* Xrow = X + (size_t)trow * G4;
        float x0 = 0.f, x1 = 0.f, x2 = 0.f, x3 = 0.f;
        if (l == 0) {
            x0 = Xrow[hidx];            x1 = Xrow[FEAT + hidx];
            x2 = Xrow[2 * FEAT + hidx]; x3 = Xrow[3 * FEAT + hidx];
        }
        float* hcur = hs[t & 1];
        if (t > 0) {
            const int prow = dir ? (trow + 1) : (trow - 1);
            const float* Hp = H + (size_t)prow * FEAT;
            float v0, v1;
            do {  // both loads issued per round — one latency, not two
                v0 = __hip_atomic_load(Hp + tid,       __ATOMIC_RELAXED, __HIP_MEMORY_SCOPE_AGENT);
                v1 = __hip_atomic_load(Hp + tid + 256, __ATOMIC_RELAXED, __HIP_MEMORY_SCOPE_AGENT);
            } while (v0 == SENT || v1 == SENT);
            hcur[tid] = v0; hcur[tid + 256] = v1;
        } else {
            hcur[tid] = 0.0f; hcur[tid + 256] = 0.0f;
        }
        __syncthreads();   // the only barrier per step (hs double-buffered)

        float4 hv4[8];
#pragma unroll
        for (int j = 0; j < 8; ++j) hv4[j] = *(const float4*)&hcur[l * 4 + j * 64];

        float dots[4];
#pragma unroll
        for (int g = 0; g < 4; ++g) {
            float s = 0.0f;
#pragma unroll
            for (int j = 0; j < 8; ++j) {
                float4 w4 = wr[g * 8 + j];
                float4 h4 = hv4[j];
                s += w4.x * h4.x + w4.y * h4.y + w4.z * h4.z + w4.w * h4.w;
            }
#pragma unroll
            for (int off = 8; off >= 1; off >>= 1) s += __shfl_xor(s, off, 64);
            dots[g] = s;
        }
        if (l == 0) {
            float gi = dots[0] + x0, gf = dots[1] + x1;
            float gg = dots[2] + x2, go = dots[3] + x3;
            float cn = sigf(gf) * c_reg + sigf(gi) * tanhf(gg);
            float hv = sigf(go) * tanhf(cn);
            c_reg = cn;
            __hip_atomic_store(H + (size_t)trow * FEAT + hidx, hv,
                               __ATOMIC_RELAXED, __HIP_MEMORY_SCOPE_AGENT);
        }
    }
}

// ---------------- fused G assembly + row-normalize ----------------
__global__ __launch_bounds__(256)
void gnorm_fuse(const float* __restrict__ S, const float* __restrict__ Hf,
                const float* __restrict__ Hb, float* __restrict__ G,
                float* __restrict__ Gn)
{
    const int row = blockIdx.x;
    const size_t base = (size_t)row * FEAT;
    const int tid = threadIdx.x;
    float v0 = S[base + tid]       + Hf[base + tid]       + Hb[base + tid];
    float v1 = S[base + tid + 256] + Hf[base + tid + 256] + Hb[base + tid + 256];
    G[base + tid] = v0;
    G[base + tid + 256] = v1;
    float s = v0 * v0 + v1 * v1;
#pragma unroll
    for (int off = 32; off >= 1; off >>= 1) s += __shfl_xor(s, off, 64);
    __shared__ float red[4];
    if ((tid & 63) == 0) red[tid >> 6] = s;
    __syncthreads();
    float tot = red[0] + red[1] + red[2] + red[3];
    float inv = 1.0f / (sqrtf(tot) + 1e-5f);
    Gn[base + tid] = v0 * inv;
    Gn[base + tid + 256] = v1 * inv;
}

// ---------------- column softmax stats over a [NQ x SLAB] slab ----------------
__global__ __launch_bounds__(256)
void colstats_partial(const float* __restrict__ A, float* __restrict__ pm,
                      float* __restrict__ pz)
{
    const int col = blockIdx.x * 256 + threadIdx.x;      // 0..511
    const int r0 = blockIdx.y * 128;
    float m = -3.0e38f, z = 0.0f;
    for (int r = 0; r < 128; ++r) {
        float v = A[(size_t)(r0 + r) * SLAB + col];
        if (v > m) { z = z * expf(m - v) + 1.0f; m = v; }
        else       { z += expf(v - m); }
    }
    pm[(size_t)blockIdx.y * SLAB + col] = m;
    pz[(size_t)blockIdx.y * SLAB + col] = z;
}

__global__ __launch_bounds__(256)
void colstats_combine(const float* __restrict__ pm, const float* __restrict__ pz,
                      float* __restrict__ cm, float* __restrict__ ciz)
{
    const int col = blockIdx.x * 256 + threadIdx.x;      // 0..511
    float m = -3.0e38f;
    for (int p = 0; p < 64; ++p) m = fmaxf(m, pm[(size_t)p * SLAB + col]);
    float z = 0.0f;
    for (int p = 0; p < 64; ++p) z += pz[(size_t)p * SLAB + col] * expf(pm[(size_t)p * SLAB + col] - m);
    cm[col] = m;
    ciz[col] = 1.0f / z;
}

// ---------------- FCE cell on one k-slice of 128 ----------------
__global__ void cell_slice(const float* __restrict__ gslab, float* __restrict__ cst,
                           float* __restrict__ hnext, const float* __restrict__ f,
                           int k0)
{
    int i = blockIdx.x * blockDim.x + threadIdx.x;
    const int st = gridDim.x * blockDim.x;
    const int n = NQ * 128;
    for (; i < n; i += st) {
        int q = i >> 7, kk = i & 127;
        float4 g = *(const float4*)(gslab + (size_t)q * 512 + kk * 4);
        int idx = q * FEAT + k0 + kk;
        float cold = cst[idx];
        float cn = sigf(g.y) * cold + sigf(g.x) * tanhf(g.z);
        float hn = sigf(g.w) * tanhf(cn) + f[idx];
        cst[idx] = cn;
        hnext[idx] = hn;
    }
}

// ---------------- launch ----------------
extern "C" void kernel_launch(void* const* d_in, const int* in_sizes, int n_in,
                              void* d_out, int out_size, void* d_ws, size_t ws_size,
                              hipStream_t stream)
{
    (void)in_sizes; (void)n_in; (void)out_size; (void)ws_size;
    const float* S     = (const float*)d_in[0];
    const float* f     = (const float*)d_in[1];
    const float* Y     = (const float*)d_in[2];
    const float* Wf_ih = (const float*)d_in[3];
    const float* Wf_hh = (const float*)d_in[4];
    const float* bf    = (const float*)d_in[5];
    const float* Wb_ih = (const float*)d_in[6];
    const float* Wb_hh = (const float*)d_in[7];
    const float* bb    = (const float*)d_in[8];
    const float* Wc_ih = (const float*)d_in[9];
    const float* Wc_hh = (const float*)d_in[10];
    const float* bc    = (const float*)d_in[11];
    float* out = (float*)d_out;

    float* ws = (float*)d_ws;
    // region 0: 16M floats, phase A/B = Xf|Xb ; phase C = r|h0|h1|cst
    float* Xf   = ws;                       // 8M
    float* Xb   = ws + (size_t)8 * 1024 * 1024;
    float* r    = ws;                       // 4M each
    float* h0   = ws + (size_t)4 * 1024 * 1024;
    float* h1   = ws + (size_t)8 * 1024 * 1024;
    float* cst  = ws + (size_t)12 * 1024 * 1024;
    size_t off  = (size_t)16 * 1024 * 1024;
    auto alloc = [&](size_t n) { float* p = ws + off; off += n; return p; };
    float* Pslab = alloc((size_t)NQ * SLAB);   // 4M (gslab; also Hf|Hb during LSTM)
    float* G     = alloc((size_t)NS * FEAT);   // 2M
    float* Gn    = alloc((size_t)NS * FEAT);   // 2M
    float* Wpack = alloc((size_t)G4 * 1536);   // 3M
    float* bpack = alloc(G4);
    float* pm    = alloc((size_t)64 * SLAB);
    float* pz    = alloc((size_t)64 * SLAB);
    float* cm    = alloc(SLAB);
    float* ciz   = alloc(SLAB);

    float* Hf = Pslab;
    float* Hb = Pslab + (size_t)2 * 1024 * 1024;

    const dim3 B256(256);

    // ---- Phase A: Xf = S@Wf_ih^T+bf, Xb = S@Wb_ih^T+bb (MFMA) ----
    mm_abt<1,0><<<dim3(16, 32), B256, 0, stream>>>(S, nullptr, nullptr, Wf_ih, FEAT, FEAT, Xf, G4, bf, FEAT);
    mm_abt<1,0><<<dim3(16, 32), B256, 0, stream>>>(S, nullptr, nullptr, Wb_ih, FEAT, FEAT, Xb, G4, bb, FEAT);

    // ---- Phase B: persistent bidirectional LSTM ----
    kfill<<<dim3(2048), B256, 0, stream>>>(Pslab, SENT, 4 * 1024 * 1024);  // Hf+Hb sentinel
    lstm_persist<<<dim3(64), B256, 0, stream>>>(Xf, Xb, Wf_hh, Wb_hh, Hf, Hb);
    gnorm_fuse<<<dim3(NS), B256, 0, stream>>>(S, Hf, Hb, G, Gn);

    // ---- Phase C prep ----
    pack_w<<<dim3(2048), B256, 0, stream>>>(Wpack, bpack, Wc_ih, Wc_hh, bc);
    kcopy<<<dim3(1024), B256, 0, stream>>>(h0, f, NQ * FEAT);   // h = f
    kzero<<<dim3(1024), B256, 0, stream>>>(cst, NQ * FEAT);     // c = 0

    // ---- Phase C: K=3 FCE iterations ----
    for (int it = 0; it < 3; ++it) {
        float* hc = (it & 1) ? h1 : h0;
        float* hx = (it & 1) ? h0 : h1;
        for (int sb = 0; sb < NS / SLAB; ++sb) {
            const float* Gs = G + (size_t)sb * SLAB * FEAT;
            mm_abt<0,0><<<dim3(4, 64), B256, 0, stream>>>(hc, nullptr, nullptr, Gs, FEAT, FEAT, Pslab, SLAB, nullptr, FEAT);
            colstats_partial<<<dim3(2, 64), B256, 0, stream>>>(Pslab, pm, pz);
            colstats_combine<<<dim3(2), B256, 0, stream>>>(pm, pz, cm, ciz);
            // exp fused into mm_ab A-stage
            if (sb == 0) mm_ab<0,1><<<dim3(4, 64), B256, 0, stream>>>(Pslab, SLAB, Gs, FEAT, r, FEAT, SLAB, cm, ciz);
            else         mm_ab<1,1><<<dim3(4, 64), B256, 0, stream>>>(Pslab, SLAB, Gs, FEAT, r, FEAT, SLAB, cm, ciz);
        }
        for (int sl = 0; sl < 4; ++sl) {
            mm_abt<1,1><<<dim3(4, 64), B256, 0, stream>>>(f, r, hc,
                Wpack + (size_t)sl * 512 * 1536, FEAT, 1536, Pslab, 512, bpack + sl * 512, 1536);
            cell_slice<<<dim3(1024), B256, 0, stream>>>(Pslab, cst, hx, f, sl * 128);
        }
    }

    // ---- Phase D: out = log(softmax_col(h @ Gn^T) @ Y), slab by slab ----
    for (int sb = 0; sb < NS / SLAB; ++sb) {
        const float* Gs = Gn + (size_t)sb * SLAB * FEAT;
        mm_abt<0,0><<<dim3(4, 64), B256, 0, stream>>>(h1, nullptr, nullptr, Gs, FEAT, FEAT, Pslab, SLAB, nullptr, FEAT);
        colstats_partial<<<dim3(2, 64), B256, 0, stream>>>(Pslab, pm, pz);
        colstats_combine<<<dim3(2), B256, 0, stream>>>(pm, pz, cm, ciz);
        if (sb == 0) gemm_ab<0,1><<<dim3(1, 64), B256, 0, stream>>>(Pslab, SLAB, Y + (size_t)sb * SLAB * NC, NC, out, NC, SLAB, cm, ciz);
        else         gemm_ab<1,1><<<dim3(1, 64), B256, 0, stream>>>(Pslab, SLAB, Y + (size_t)sb * SLAB * NC, NC, out, NC, SLAB, cm, ciz);
    }
    klog<<<dim3(512), B256, 0, stream>>>(out, NQ * NC);
}